// Round 2
// baseline (2879.900 us; speedup 1.0000x reference)
//
#include <hip/hip_runtime.h>
#include <hip/hip_bf16.h>

#define NNODES 50000
#define NEDGES 400000
#define NGRAPH 16
#define CHUNK_ROWS 6272   // multiple of 64; 8 chunks cover 50000 nodes

// ---------------------------------------------------------------------------
// fallback: write zeros to out (signals "workspace too small" as a clean
// absmax failure instead of an abort)
__global__ __launch_bounds__(64) void zero_out_k(float* out, int n) {
    int i = blockIdx.x * 64 + threadIdx.x;
    if (i < n) out[i] = 0.0f;
}

// k0: zero counters / accumulators
__global__ __launch_bounds__(256) void init_k(int* deg_cnt, int* cursor,
                                              float* gsum, int* gcnt, int n) {
    int i = blockIdx.x * 256 + threadIdx.x;
    if (i < n) { deg_cnt[i] = 0; cursor[i] = 0; }
    if (i < NGRAPH * 512) gsum[i] = 0.0f;
    if (i < NGRAPH) gcnt[i] = 0;
}

// k1: in-degree histogram over col (real edges only; self-loop added later)
__global__ __launch_bounds__(256) void deg_k(const int* __restrict__ col,
                                             int* __restrict__ deg_cnt, int e) {
    int i = blockIdx.x * 256 + threadIdx.x;
    if (i < e) atomicAdd(&deg_cnt[col[i]], 1);
}

// k2: dis = rsqrt(deg + 1)  (+1 = self loop)
__global__ __launch_bounds__(256) void dis_k(const int* __restrict__ deg_cnt,
                                             float* __restrict__ dis, int n) {
    int i = blockIdx.x * 256 + threadIdx.x;
    if (i < n) dis[i] = rsqrtf((float)(deg_cnt[i] + 1));
}

// k3: single-block exclusive scan of deg_cnt -> offsets[0..n], offsets[n]=E
__global__ __launch_bounds__(1024) void scan_k(const int* __restrict__ cnt,
                                               int* __restrict__ offs, int n) {
    __shared__ int sbuf[1024];
    int t = threadIdx.x;
    int chunk = (n + 1023) / 1024;
    int beg = t * chunk;
    int end = min(beg + chunk, n);
    int s = 0;
    for (int i = beg; i < end; ++i) s += cnt[i];
    sbuf[t] = s;
    __syncthreads();
    for (int off = 1; off < 1024; off <<= 1) {
        int v = (t >= off) ? sbuf[t - off] : 0;
        __syncthreads();
        sbuf[t] += v;
        __syncthreads();
    }
    int run = sbuf[t] - s;  // exclusive prefix for this thread's chunk
    for (int i = beg; i < end; ++i) { offs[i] = run; run += cnt[i]; }
    if (t == 1023) offs[n] = sbuf[1023];
}

// k4: scatter edges into CSR sorted by destination; weight = dis[src]
__global__ __launch_bounds__(256) void scatter_k(const int* __restrict__ row,
                                                 const int* __restrict__ col,
                                                 const int* __restrict__ offs,
                                                 int* __restrict__ cursor,
                                                 int* __restrict__ ssrc,
                                                 float* __restrict__ sw,
                                                 const float* __restrict__ dis, int e) {
    int i = blockIdx.x * 256 + threadIdx.x;
    if (i >= e) return;
    int d = col[i];
    int p = offs[d] + atomicAdd(&cursor[d], 1);
    int s = row[i];
    ssrc[p] = s;
    sw[p]   = dis[s];
}

// k5: aggregate x (F=3): out[d] = dis[d] * (sum_e dis[src]*x[src] + dis[d]*x[d])
__global__ __launch_bounds__(256) void agg3_k(const float* __restrict__ x,
                                              float* __restrict__ out,
                                              const int* __restrict__ offs,
                                              const int* __restrict__ ssrc,
                                              const float* __restrict__ sw,
                                              const float* __restrict__ dis, int n) {
    int d = blockIdx.x * 256 + threadIdx.x;
    if (d >= n) return;
    float dd = dis[d];
    float a0 = dd * x[d * 3 + 0];
    float a1 = dd * x[d * 3 + 1];
    float a2 = dd * x[d * 3 + 2];
    int beg = offs[d], end = offs[d + 1];
    for (int e = beg; e < end; ++e) {
        int s = ssrc[e];
        float w = sw[e];
        a0 += w * x[s * 3 + 0];
        a1 += w * x[s * 3 + 1];
        a2 += w * x[s * 3 + 2];
    }
    out[d * 3 + 0] = dd * a0;
    out[d * 3 + 1] = dd * a1;
    out[d * 3 + 2] = dd * a2;
}

// k6: tiny GEMM layer 1: h1 = relu(aggx[N,3] @ W1[3,512] + b1)
__global__ __launch_bounds__(256) void gemm1_k(const float* __restrict__ aggx,
                                               const float* __restrict__ W1,
                                               const float* __restrict__ b1,
                                               float* __restrict__ h1) {
    int d = blockIdx.x;
    int t = threadIdx.x;
    float a0 = aggx[d * 3 + 0], a1 = aggx[d * 3 + 1], a2 = aggx[d * 3 + 2];
    for (int f = t; f < 512; f += 256) {
        float v = b1[f] + a0 * W1[f] + a1 * W1[512 + f] + a2 * W1[1024 + f];
        h1[(long)d * 512 + f] = fmaxf(v, 0.0f);
    }
}

// k7: aggregation at F=512, one block per node, optional bias+relu epilogue
__global__ __launch_bounds__(256) void agg512_k(const float* __restrict__ in,
                                                float* __restrict__ out,
                                                const int* __restrict__ offs,
                                                const int* __restrict__ ssrc,
                                                const float* __restrict__ sw,
                                                const float* __restrict__ dis,
                                                const float* __restrict__ bias,
                                                int relu) {
    int d = blockIdx.x;
    int t = threadIdx.x;
    float dd = dis[d];
    const float* ind = in + (long)d * 512;
    float acc0 = dd * ind[t];
    float acc1 = dd * ind[t + 256];
    int beg = offs[d], end = offs[d + 1];
    for (int e = beg; e < end; ++e) {
        int s  = ssrc[e];
        float w = sw[e];
        const float* ins = in + (long)s * 512;
        acc0 += w * ins[t];
        acc1 += w * ins[t + 256];
    }
    acc0 *= dd; acc1 *= dd;
    if (bias) { acc0 += bias[t]; acc1 += bias[t + 256]; }
    if (relu) { acc0 = fmaxf(acc0, 0.0f); acc1 = fmaxf(acc1, 0.0f); }
    out[(long)d * 512 + t]       = acc0;
    out[(long)d * 512 + t + 256] = acc1;
}

// k8: fp32 tiled GEMM  C[M,N] = epi(A[M,K] @ B[K,N] + bias)
// BM=BN=64, BK=16, 256 threads, 4x4 micro-tile per thread
__global__ __launch_bounds__(256) void gemm_k(const float* __restrict__ A,
                                              const float* __restrict__ B,
                                              const float* __restrict__ bias,
                                              float* __restrict__ C,
                                              int M, int N, int K, int relu) {
    __shared__ float Ast[16][65];   // [k][m], +1 pad
    __shared__ float Bs[16][64];    // [k][n]
    int tid = threadIdx.x;
    int tx = tid & 15, ty = tid >> 4;
    int bm = blockIdx.y * 64;
    int bn = blockIdx.x * 64;

    int a_m = tid & 63;
    int a_k = (tid >> 6) << 2;
    int b_k = tid >> 4;
    int b_n = (tid & 15) << 2;

    int arow = bm + a_m;
    bool row_ok = arow < M;

    float acc[4][4] = {};

    for (int k0 = 0; k0 < K; k0 += 16) {
        float4 av = make_float4(0.f, 0.f, 0.f, 0.f);
        if (row_ok) av = *(const float4*)&A[(long)arow * K + k0 + a_k];
        Ast[a_k + 0][a_m] = av.x;
        Ast[a_k + 1][a_m] = av.y;
        Ast[a_k + 2][a_m] = av.z;
        Ast[a_k + 3][a_m] = av.w;
        *(float4*)&Bs[b_k][b_n] = *(const float4*)&B[(long)(k0 + b_k) * N + bn + b_n];
        __syncthreads();
#pragma unroll
        for (int k = 0; k < 16; ++k) {
            float a0 = Ast[k][ty * 4 + 0];
            float a1 = Ast[k][ty * 4 + 1];
            float a2 = Ast[k][ty * 4 + 2];
            float a3 = Ast[k][ty * 4 + 3];
            float b0 = Bs[k][tx * 4 + 0];
            float b1 = Bs[k][tx * 4 + 1];
            float b2 = Bs[k][tx * 4 + 2];
            float b3 = Bs[k][tx * 4 + 3];
            acc[0][0] += a0 * b0; acc[0][1] += a0 * b1; acc[0][2] += a0 * b2; acc[0][3] += a0 * b3;
            acc[1][0] += a1 * b0; acc[1][1] += a1 * b1; acc[1][2] += a1 * b2; acc[1][3] += a1 * b3;
            acc[2][0] += a2 * b0; acc[2][1] += a2 * b1; acc[2][2] += a2 * b2; acc[2][3] += a2 * b3;
            acc[3][0] += a3 * b0; acc[3][1] += a3 * b1; acc[3][2] += a3 * b2; acc[3][3] += a3 * b3;
        }
        __syncthreads();
    }

#pragma unroll
    for (int i = 0; i < 4; ++i) {
        int r = bm + ty * 4 + i;
        if (r >= M) break;
        int c = bn + tx * 4;
        float4 v;
        v.x = acc[i][0]; v.y = acc[i][1]; v.z = acc[i][2]; v.w = acc[i][3];
        if (bias) {
            v.x += bias[c + 0]; v.y += bias[c + 1]; v.z += bias[c + 2]; v.w += bias[c + 3];
        }
        if (relu) {
            v.x = fmaxf(v.x, 0.f); v.y = fmaxf(v.y, 0.f);
            v.z = fmaxf(v.z, 0.f); v.w = fmaxf(v.w, 0.f);
        }
        *(float4*)&C[(long)r * N + c] = v;
    }
}

// k9: per-graph node counts
__global__ __launch_bounds__(256) void count_k(const int* __restrict__ batch,
                                               int* __restrict__ gcnt, int n) {
    int i = blockIdx.x * 256 + threadIdx.x;
    if (i < n) atomicAdd(&gcnt[batch[i]], 1);
}

// k10: pooled sums via per-block LDS accumulators (16 graphs x 512 feats)
__global__ __launch_bounds__(256) void pool_k(const float* __restrict__ h,
                                              const int* __restrict__ batch,
                                              float* __restrict__ gsum, int n) {
    __shared__ float ls[NGRAPH * 512];
    int t = threadIdx.x;
    for (int i = t; i < NGRAPH * 512; i += 256) ls[i] = 0.0f;
    __syncthreads();
    for (int d = blockIdx.x; d < n; d += gridDim.x) {
        int g = batch[d];
        const float* hd = h + (long)d * 512;
        ls[g * 512 + t]       += hd[t];
        ls[g * 512 + t + 256] += hd[t + 256];
    }
    __syncthreads();
    for (int i = t; i < NGRAPH * 512; i += 256) atomicAdd(&gsum[i], ls[i]);
}

// k11: head MLP: out[g] = (relu(pooled @ fcw1 + fcb1)) @ fcw2 + fcb2
__global__ __launch_bounds__(128) void fc_k(const float* __restrict__ gsum,
                                            const int* __restrict__ gcnt,
                                            const float* __restrict__ fcw1,
                                            const float* __restrict__ fcb1,
                                            const float* __restrict__ fcw2,
                                            const float* __restrict__ fcb2,
                                            float* __restrict__ out) {
    int g = blockIdx.x;
    int t = threadIdx.x;  // 128
    __shared__ float pooled[512];
    __shared__ float red[128];
    float inv = 1.0f / fmaxf((float)gcnt[g], 1.0f);
    for (int i = t; i < 512; i += 128) pooled[i] = gsum[g * 512 + i] * inv;
    __syncthreads();
    float s = fcb1[t];
    for (int k = 0; k < 512; ++k) s += pooled[k] * fcw1[k * 128 + t];
    s = fmaxf(s, 0.0f);
    red[t] = s * fcw2[t];
    __syncthreads();
    for (int off = 64; off > 0; off >>= 1) {
        if (t < off) red[t] += red[t + off];
        __syncthreads();
    }
    if (t == 0) out[g] = red[0] + fcb2[0];
}

extern "C" void kernel_launch(void* const* d_in, const int* in_sizes, int n_in,
                              void* d_out, int out_size, void* d_ws, size_t ws_size,
                              hipStream_t stream) {
    const float* x    = (const float*)d_in[0];
    const int*   ei   = (const int*)d_in[1];   // [2, E]
    const int*   batch= (const int*)d_in[2];
    const float* W1   = (const float*)d_in[3];
    const float* b1   = (const float*)d_in[4];
    const float* W2   = (const float*)d_in[5];
    const float* b2   = (const float*)d_in[6];
    const float* W3   = (const float*)d_in[7];
    const float* b3   = (const float*)d_in[8];
    const float* fcw1 = (const float*)d_in[9];
    const float* fcb1 = (const float*)d_in[10];
    const float* fcw2 = (const float*)d_in[11];
    const float* fcb2 = (const float*)d_in[12];
    float* out = (float*)d_out;

    const int N = in_sizes[0] / 3;      // 50000
    const int E = in_sizes[1] / 2;      // 400000
    const int* row = ei;
    const int* col = ei + E;

    // ---- workspace layout (bump allocator, 256B aligned) ----
    size_t used = 0;
    auto need = [&](size_t bytes) {
        size_t off = used;
        used += (bytes + 255) & ~(size_t)255;
        return off;
    };
    size_t o_deg  = need((size_t)N * 4);
    size_t o_cur  = need((size_t)N * 4);
    size_t o_dis  = need((size_t)N * 4);
    size_t o_offs = need((size_t)(N + 1) * 4);
    size_t o_ssrc = need((size_t)E * 4);
    size_t o_sw   = need((size_t)E * 4);
    size_t o_aggx = need((size_t)N * 3 * 4);
    size_t o_gsum = need((size_t)NGRAPH * 512 * 4);
    size_t o_gcnt = need((size_t)NGRAPH * 4);
    size_t o_bufA = need((size_t)N * 512 * 4);             // h1 / g3
    size_t o_bufB = need((size_t)N * 512 * 4);             // agg1 / h3
    size_t o_bufC = need((size_t)CHUNK_ROWS * 1024 * 4);   // h2 chunk

    if (used > ws_size) {
        // Workspace too small for this layout — emit clean zeros so the
        // bench fails with a recognizable absmax instead of a page fault.
        hipLaunchKernelGGL(zero_out_k, dim3((out_size + 63) / 64), dim3(64), 0, stream,
                           out, out_size);
        return;
    }

    char* base = (char*)d_ws;
    int*   deg_cnt = (int*)  (base + o_deg);
    int*   cursor  = (int*)  (base + o_cur);
    float* dis     = (float*)(base + o_dis);
    int*   offs    = (int*)  (base + o_offs);
    int*   ssrc    = (int*)  (base + o_ssrc);
    float* sw      = (float*)(base + o_sw);
    float* aggx    = (float*)(base + o_aggx);
    float* gsum    = (float*)(base + o_gsum);
    int*   gcnt    = (int*)  (base + o_gcnt);
    float* bufA    = (float*)(base + o_bufA);
    float* bufB    = (float*)(base + o_bufB);
    float* bufC    = (float*)(base + o_bufC);
    (void)n_in;

    int gN = (N + 255) / 256;
    int gE = (E + 255) / 256;

    // CSR build + norm
    hipLaunchKernelGGL(init_k, dim3(gN), dim3(256), 0, stream, deg_cnt, cursor, gsum, gcnt, N);
    hipLaunchKernelGGL(deg_k, dim3(gE), dim3(256), 0, stream, col, deg_cnt, E);
    hipLaunchKernelGGL(dis_k, dim3(gN), dim3(256), 0, stream, deg_cnt, dis, N);
    hipLaunchKernelGGL(scan_k, dim3(1), dim3(1024), 0, stream, deg_cnt, offs, N);
    hipLaunchKernelGGL(scatter_k, dim3(gE), dim3(256), 0, stream, row, col, offs, cursor, ssrc, sw, dis, E);

    // layer 1: agg(F=3) then GEMM 3->512 (+b1, relu) -> bufA = h1
    hipLaunchKernelGGL(agg3_k, dim3(gN), dim3(256), 0, stream, x, aggx, offs, ssrc, sw, dis, N);
    hipLaunchKernelGGL(gemm1_k, dim3(N), dim3(256), 0, stream, aggx, W1, b1, bufA);

    // layer 2 agg: bufB = A_norm * h1   (F=512)
    hipLaunchKernelGGL(agg512_k, dim3(N), dim3(256), 0, stream, bufA, bufB, offs, ssrc, sw, dis, (const float*)nullptr, 0);

    // layers 2+3 GEMMs, chunked over nodes to bound h2 footprint:
    //   h2_c = relu(bufB_c @ W2 + b2)   [CHUNK,1024]  -> bufC
    //   g3_c = h2_c @ W3                [CHUNK,512]   -> bufA_c (h1 dead)
    for (int base_row = 0; base_row < N; base_row += CHUNK_ROWS) {
        int mc = min(CHUNK_ROWS, N - base_row);
        hipLaunchKernelGGL(gemm_k, dim3(1024 / 64, (mc + 63) / 64), dim3(256), 0, stream,
                           bufB + (size_t)base_row * 512, W2, b2, bufC, mc, 1024, 512, 1);
        hipLaunchKernelGGL(gemm_k, dim3(512 / 64, (mc + 63) / 64), dim3(256), 0, stream,
                           bufC, W3, (const float*)nullptr, bufA + (size_t)base_row * 512,
                           mc, 512, 1024, 0);
    }

    // layer 3 agg (+b3, relu): bufB = relu(A_norm * g3 + b3)
    hipLaunchKernelGGL(agg512_k, dim3(N), dim3(256), 0, stream, bufA, bufB, offs, ssrc, sw, dis, b3, 1);

    // mean pool + head
    hipLaunchKernelGGL(count_k, dim3(gN), dim3(256), 0, stream, batch, gcnt, N);
    hipLaunchKernelGGL(pool_k, dim3(128), dim3(256), 0, stream, bufB, batch, gsum, N);
    hipLaunchKernelGGL(fc_k, dim3(NGRAPH), dim3(128), 0, stream, gsum, gcnt, fcw1, fcb1, fcw2, fcb2, out);
}

// Round 3
// 936.881 us; speedup vs baseline: 3.0739x; 3.0739x over previous
//
#include <hip/hip_runtime.h>
#include <hip/hip_bf16.h>

#define NNODES 50000
#define NEDGES 400000
#define NGRAPH 16

typedef __attribute__((ext_vector_type(4))) float floatx4;
typedef __attribute__((ext_vector_type(8))) short short8;

// ---------------------------------------------------------------------------
// fallback: write zeros to out (signals "workspace too small" cleanly)
__global__ __launch_bounds__(64) void zero_out_k(float* out, int n) {
    int i = blockIdx.x * 64 + threadIdx.x;
    if (i < n) out[i] = 0.0f;
}

// k0: zero counters / accumulators
__global__ __launch_bounds__(256) void init_k(int* deg_cnt, int* cursor,
                                              float* gsum, int* gcnt, int n) {
    int i = blockIdx.x * 256 + threadIdx.x;
    if (i < n) { deg_cnt[i] = 0; cursor[i] = 0; }
    if (i < NGRAPH * 512) gsum[i] = 0.0f;
    if (i < NGRAPH) gcnt[i] = 0;
}

// k1: in-degree histogram over col
__global__ __launch_bounds__(256) void deg_k(const int* __restrict__ col,
                                             int* __restrict__ deg_cnt, int e) {
    int i = blockIdx.x * 256 + threadIdx.x;
    if (i < e) atomicAdd(&deg_cnt[col[i]], 1);
}

// k2: dis = rsqrt(deg + 1)
__global__ __launch_bounds__(256) void dis_k(const int* __restrict__ deg_cnt,
                                             float* __restrict__ dis, int n) {
    int i = blockIdx.x * 256 + threadIdx.x;
    if (i < n) dis[i] = rsqrtf((float)(deg_cnt[i] + 1));
}

// k3: single-block exclusive scan
__global__ __launch_bounds__(1024) void scan_k(const int* __restrict__ cnt,
                                               int* __restrict__ offs, int n) {
    __shared__ int sbuf[1024];
    int t = threadIdx.x;
    int chunk = (n + 1023) / 1024;
    int beg = t * chunk;
    int end = min(beg + chunk, n);
    int s = 0;
    for (int i = beg; i < end; ++i) s += cnt[i];
    sbuf[t] = s;
    __syncthreads();
    for (int off = 1; off < 1024; off <<= 1) {
        int v = (t >= off) ? sbuf[t - off] : 0;
        __syncthreads();
        sbuf[t] += v;
        __syncthreads();
    }
    int run = sbuf[t] - s;
    for (int i = beg; i < end; ++i) { offs[i] = run; run += cnt[i]; }
    if (t == 1023) offs[n] = sbuf[1023];
}

// k4: scatter edges into dest-keyed CSR; weight = dis[src]
__global__ __launch_bounds__(256) void scatter_k(const int* __restrict__ row,
                                                 const int* __restrict__ col,
                                                 const int* __restrict__ offs,
                                                 int* __restrict__ cursor,
                                                 int* __restrict__ ssrc,
                                                 float* __restrict__ sw,
                                                 const float* __restrict__ dis, int e) {
    int i = blockIdx.x * 256 + threadIdx.x;
    if (i >= e) return;
    int d = col[i];
    int p = offs[d] + atomicAdd(&cursor[d], 1);
    int s = row[i];
    ssrc[p] = s;
    sw[p]   = dis[s];
}

// k5: aggregate x (F=3) fp32
__global__ __launch_bounds__(256) void agg3_k(const float* __restrict__ x,
                                              float* __restrict__ out,
                                              const int* __restrict__ offs,
                                              const int* __restrict__ ssrc,
                                              const float* __restrict__ sw,
                                              const float* __restrict__ dis, int n) {
    int d = blockIdx.x * 256 + threadIdx.x;
    if (d >= n) return;
    float dd = dis[d];
    float a0 = dd * x[d * 3 + 0];
    float a1 = dd * x[d * 3 + 1];
    float a2 = dd * x[d * 3 + 2];
    int beg = offs[d], end = offs[d + 1];
    for (int e = beg; e < end; ++e) {
        int s = ssrc[e];
        float w = sw[e];
        a0 += w * x[s * 3 + 0];
        a1 += w * x[s * 3 + 1];
        a2 += w * x[s * 3 + 2];
    }
    out[d * 3 + 0] = dd * a0;
    out[d * 3 + 1] = dd * a1;
    out[d * 3 + 2] = dd * a2;
}

// k6: h1 = relu(aggx[N,3] @ W1[3,512] + b1) -> bf16
__global__ __launch_bounds__(256) void gemm1_k(const float* __restrict__ aggx,
                                               const float* __restrict__ W1,
                                               const float* __restrict__ b1,
                                               __hip_bfloat16* __restrict__ h1) {
    int d = blockIdx.x;
    int t = threadIdx.x;
    float a0 = aggx[d * 3 + 0], a1 = aggx[d * 3 + 1], a2 = aggx[d * 3 + 2];
    for (int f = t; f < 512; f += 256) {
        float v = b1[f] + a0 * W1[f] + a1 * W1[512 + f] + a2 * W1[1024 + f];
        h1[(size_t)d * 512 + f] = __float2bfloat16(fmaxf(v, 0.0f));
    }
}

__device__ inline float b2f(unsigned int u) { return __uint_as_float(u << 16); }

// k7: aggregation F=512 on bf16 data, fp32 accumulate, bf16 out.
// thread t handles feats 2t, 2t+1 (one dword per row access -> coalesced)
__global__ __launch_bounds__(256) void agg512bf_k(const __hip_bfloat16* __restrict__ in,
                                                  __hip_bfloat16* __restrict__ out,
                                                  const int* __restrict__ offs,
                                                  const int* __restrict__ ssrc,
                                                  const float* __restrict__ sw,
                                                  const float* __restrict__ dis,
                                                  const float* __restrict__ bias,
                                                  int relu) {
    int d = blockIdx.x;
    int t = threadIdx.x;
    float dd = dis[d];
    unsigned int p = *(const unsigned int*)&in[(size_t)d * 512 + 2 * t];
    float acc0 = dd * b2f(p & 0xffffu);
    float acc1 = dd * b2f(p >> 16);
    int beg = offs[d], end = offs[d + 1];
    for (int e = beg; e < end; ++e) {
        int s  = ssrc[e];
        float w = sw[e];
        unsigned int q = *(const unsigned int*)&in[(size_t)s * 512 + 2 * t];
        acc0 += w * b2f(q & 0xffffu);
        acc1 += w * b2f(q >> 16);
    }
    acc0 *= dd; acc1 *= dd;
    if (bias) { acc0 += bias[2 * t]; acc1 += bias[2 * t + 1]; }
    if (relu) { acc0 = fmaxf(acc0, 0.0f); acc1 = fmaxf(acc1, 0.0f); }
    __hip_bfloat16 o0 = __float2bfloat16(acc0);
    __hip_bfloat16 o1 = __float2bfloat16(acc1);
    unsigned int ob = ((unsigned int)*(unsigned short*)&o1 << 16) |
                       (unsigned int)*(unsigned short*)&o0;
    *(unsigned int*)&out[(size_t)d * 512 + 2 * t] = ob;
}

// k-tc: tiled transpose + f32->bf16 convert: W[K][N] -> Wt[N][K]
__global__ __launch_bounds__(256) void tcvt_k(const float* __restrict__ W,
                                              __hip_bfloat16* __restrict__ Wt,
                                              int K, int N) {
    __shared__ float tile[32][33];
    int t = threadIdx.x;
    int bn = blockIdx.x * 32;   // n
    int bk = blockIdx.y * 32;   // k
    int c = t & 31, r0 = t >> 5;     // 8 rows per pass
#pragma unroll
    for (int j = 0; j < 4; ++j) {
        int r = r0 + j * 8;
        tile[r][c] = W[(size_t)(bk + r) * N + bn + c];
    }
    __syncthreads();
#pragma unroll
    for (int j = 0; j < 4; ++j) {
        int r = r0 + j * 8;
        Wt[(size_t)(bn + r) * K + bk + c] = __float2bfloat16(tile[c][r]);
    }
}

// k8: bf16 MFMA GEMM: C[M,N] = epi(A[M,K] @ Bt[N,K]^T + bias), all bf16 in,
// bf16 out. 128x128 tile, BK=32, 256 thr = 4 waves (2x2), 16x16x32 MFMA.
#define LSTR 40   // LDS row stride in bf16 elems (32 + 8 pad)
__global__ __launch_bounds__(256) void mfma_gemm_k(const __hip_bfloat16* __restrict__ A,
                                                   const __hip_bfloat16* __restrict__ Bt,
                                                   const float* __restrict__ bias,
                                                   __hip_bfloat16* __restrict__ C,
                                                   int M, int N, int K, int relu) {
    __shared__ short smem[17408];          // 34816 B: staging (2*5120) / epi (128*136)
    short* As = smem;                      // [128][LSTR]
    short* Bs = smem + 128 * LSTR;         // [128][LSTR]
    short* Cs = smem;                      // [128][136] (epilogue reuse)

    int tid  = threadIdx.x;
    int lane = tid & 63;
    int wave = tid >> 6;
    int wm = (wave >> 1) * 64;
    int wn = (wave & 1) * 64;
    int fr = lane & 15;        // m (A) / n (B) within 16x16 tile
    int kg = lane >> 4;        // k-group 0..3 (8 elems each)

    int bm = blockIdx.y * 128;
    int bn = blockIdx.x * 128;

    floatx4 acc[4][4] = {};

    for (int k0 = 0; k0 < K; k0 += 32) {
        // stage A tile (128x32) and Bt tile (128x32), 16B per thread x2 each
#pragma unroll
        for (int i = 0; i < 2; ++i) {
            int c  = tid + 256 * i;       // 0..511
            int r  = c >> 2;              // 0..127
            int cc = c & 3;               // 8-elem chunk along k
            short8 av = {};
            int garow = bm + r;
            if (garow < M) av = *(const short8*)&A[(size_t)garow * K + k0 + cc * 8];
            *(short8*)&As[r * LSTR + cc * 8] = av;
            *(short8*)&Bs[r * LSTR + cc * 8] =
                *(const short8*)&Bt[(size_t)(bn + r) * K + k0 + cc * 8];
        }
        __syncthreads();

        short8 af[4], bf[4];
#pragma unroll
        for (int mi = 0; mi < 4; ++mi)
            af[mi] = *(short8*)&As[(wm + mi * 16 + fr) * LSTR + kg * 8];
#pragma unroll
        for (int ni = 0; ni < 4; ++ni)
            bf[ni] = *(short8*)&Bs[(wn + ni * 16 + fr) * LSTR + kg * 8];
#pragma unroll
        for (int mi = 0; mi < 4; ++mi)
#pragma unroll
            for (int ni = 0; ni < 4; ++ni)
                acc[mi][ni] = __builtin_amdgcn_mfma_f32_16x16x32_bf16(
                    af[mi], bf[ni], acc[mi][ni], 0, 0, 0);
        __syncthreads();
    }

    // epilogue: bias+relu, repack through LDS, coalesced 16B stores
#pragma unroll
    for (int mi = 0; mi < 4; ++mi) {
#pragma unroll
        for (int ni = 0; ni < 4; ++ni) {
            int rl = wm + mi * 16 + (lane >> 4) * 4;
            int cl = wn + ni * 16 + (lane & 15);
            float bv = bias ? bias[bn + cl] : 0.0f;
#pragma unroll
            for (int r = 0; r < 4; ++r) {
                float v = acc[mi][ni][r] + bv;
                if (relu) v = fmaxf(v, 0.0f);
                __hip_bfloat16 h = __float2bfloat16(v);
                Cs[(rl + r) * 136 + cl] = *(short*)&h;
            }
        }
    }
    __syncthreads();
#pragma unroll
    for (int i = 0; i < 8; ++i) {
        int c  = tid + 256 * i;      // 0..2047
        int rr = c >> 4;             // 0..127
        int cc = c & 15;
        int grow = bm + rr;
        if (grow < M)
            *(short8*)&C[(size_t)grow * N + bn + cc * 8] =
                *(short8*)&Cs[rr * 136 + cc * 8];
    }
}

// k9: per-graph node counts
__global__ __launch_bounds__(256) void count_k(const int* __restrict__ batch,
                                               int* __restrict__ gcnt, int n) {
    int i = blockIdx.x * 256 + threadIdx.x;
    if (i < n) atomicAdd(&gcnt[batch[i]], 1);
}

// k10: pooled sums, bf16 input, LDS fp32 accumulators
__global__ __launch_bounds__(256) void pool_k(const __hip_bfloat16* __restrict__ h,
                                              const int* __restrict__ batch,
                                              float* __restrict__ gsum, int n) {
    __shared__ float ls[NGRAPH * 512];
    int t = threadIdx.x;
    for (int i = t; i < NGRAPH * 512; i += 256) ls[i] = 0.0f;
    __syncthreads();
    for (int d = blockIdx.x; d < n; d += gridDim.x) {
        int g = batch[d];
        unsigned int q = *(const unsigned int*)&h[(size_t)d * 512 + 2 * t];
        ls[g * 512 + 2 * t]     += b2f(q & 0xffffu);
        ls[g * 512 + 2 * t + 1] += b2f(q >> 16);
    }
    __syncthreads();
    for (int i = t; i < NGRAPH * 512; i += 256) atomicAdd(&gsum[i], ls[i]);
}

// k11: head MLP (fp32)
__global__ __launch_bounds__(128) void fc_k(const float* __restrict__ gsum,
                                            const int* __restrict__ gcnt,
                                            const float* __restrict__ fcw1,
                                            const float* __restrict__ fcb1,
                                            const float* __restrict__ fcw2,
                                            const float* __restrict__ fcb2,
                                            float* __restrict__ out) {
    int g = blockIdx.x;
    int t = threadIdx.x;  // 128
    __shared__ float pooled[512];
    __shared__ float red[128];
    float inv = 1.0f / fmaxf((float)gcnt[g], 1.0f);
    for (int i = t; i < 512; i += 128) pooled[i] = gsum[g * 512 + i] * inv;
    __syncthreads();
    float s = fcb1[t];
    for (int k = 0; k < 512; ++k) s += pooled[k] * fcw1[k * 128 + t];
    s = fmaxf(s, 0.0f);
    red[t] = s * fcw2[t];
    __syncthreads();
    for (int off = 64; off > 0; off >>= 1) {
        if (t < off) red[t] += red[t + off];
        __syncthreads();
    }
    if (t == 0) out[g] = red[0] + fcb2[0];
}

extern "C" void kernel_launch(void* const* d_in, const int* in_sizes, int n_in,
                              void* d_out, int out_size, void* d_ws, size_t ws_size,
                              hipStream_t stream) {
    const float* x    = (const float*)d_in[0];
    const int*   ei   = (const int*)d_in[1];   // [2, E]
    const int*   batch= (const int*)d_in[2];
    const float* W1   = (const float*)d_in[3];
    const float* b1   = (const float*)d_in[4];
    const float* W2   = (const float*)d_in[5];
    const float* b2   = (const float*)d_in[6];
    const float* W3   = (const float*)d_in[7];
    const float* b3   = (const float*)d_in[8];
    const float* fcw1 = (const float*)d_in[9];
    const float* fcb1 = (const float*)d_in[10];
    const float* fcw2 = (const float*)d_in[11];
    const float* fcb2 = (const float*)d_in[12];
    float* out = (float*)d_out;

    const int N = in_sizes[0] / 3;      // 50000
    const int E = in_sizes[1] / 2;      // 400000
    const int* row = ei;
    const int* col = ei + E;

    // ---- workspace layout ----
    size_t used = 0;
    auto need = [&](size_t bytes) {
        size_t off = used;
        used += (bytes + 255) & ~(size_t)255;
        return off;
    };
    size_t o_deg  = need((size_t)N * 4);
    size_t o_cur  = need((size_t)N * 4);
    size_t o_dis  = need((size_t)N * 4);
    size_t o_offs = need((size_t)(N + 1) * 4);
    size_t o_ssrc = need((size_t)E * 4);
    size_t o_sw   = need((size_t)E * 4);
    size_t o_aggx = need((size_t)N * 3 * 4);
    size_t o_gsum = need((size_t)NGRAPH * 512 * 4);
    size_t o_gcnt = need((size_t)NGRAPH * 4);
    size_t o_w2t  = need((size_t)512 * 1024 * 2);   // W2^T bf16 [1024][512]
    size_t o_w3t  = need((size_t)1024 * 512 * 2);   // W3^T bf16 [512][1024]
    size_t o_bufX = need((size_t)N * 512 * 2);      // h1 -> g3   (bf16)
    size_t o_bufY = need((size_t)N * 512 * 2);      // agg1 -> h3 (bf16)
    size_t o_bufZ = need((size_t)N * 1024 * 2);     // h2         (bf16)

    if (used > ws_size) {
        hipLaunchKernelGGL(zero_out_k, dim3((out_size + 63) / 64), dim3(64), 0, stream,
                           out, out_size);
        return;
    }

    char* base = (char*)d_ws;
    int*   deg_cnt = (int*)  (base + o_deg);
    int*   cursor  = (int*)  (base + o_cur);
    float* dis     = (float*)(base + o_dis);
    int*   offs    = (int*)  (base + o_offs);
    int*   ssrc    = (int*)  (base + o_ssrc);
    float* sw      = (float*)(base + o_sw);
    float* aggx    = (float*)(base + o_aggx);
    float* gsum    = (float*)(base + o_gsum);
    int*   gcnt    = (int*)  (base + o_gcnt);
    __hip_bfloat16* w2t  = (__hip_bfloat16*)(base + o_w2t);
    __hip_bfloat16* w3t  = (__hip_bfloat16*)(base + o_w3t);
    __hip_bfloat16* bufX = (__hip_bfloat16*)(base + o_bufX);
    __hip_bfloat16* bufY = (__hip_bfloat16*)(base + o_bufY);
    __hip_bfloat16* bufZ = (__hip_bfloat16*)(base + o_bufZ);
    (void)n_in;

    int gN = (N + 255) / 256;
    int gE = (E + 255) / 256;

    // CSR build + norm
    hipLaunchKernelGGL(init_k, dim3(gN), dim3(256), 0, stream, deg_cnt, cursor, gsum, gcnt, N);
    hipLaunchKernelGGL(deg_k, dim3(gE), dim3(256), 0, stream, col, deg_cnt, E);
    hipLaunchKernelGGL(dis_k, dim3(gN), dim3(256), 0, stream, deg_cnt, dis, N);
    hipLaunchKernelGGL(scan_k, dim3(1), dim3(1024), 0, stream, deg_cnt, offs, N);
    hipLaunchKernelGGL(scatter_k, dim3(gE), dim3(256), 0, stream, row, col, offs, cursor, ssrc, sw, dis, E);

    // weights: transpose + bf16 convert (no deps on CSR)
    hipLaunchKernelGGL(tcvt_k, dim3(1024 / 32, 512 / 32), dim3(256), 0, stream, W2, w2t, 512, 1024);
    hipLaunchKernelGGL(tcvt_k, dim3(512 / 32, 1024 / 32), dim3(256), 0, stream, W3, w3t, 1024, 512);

    // layer 1: agg(F=3) fp32, then 3->512 GEMM -> h1 bf16
    hipLaunchKernelGGL(agg3_k, dim3(gN), dim3(256), 0, stream, x, aggx, offs, ssrc, sw, dis, N);
    hipLaunchKernelGGL(gemm1_k, dim3(N), dim3(256), 0, stream, aggx, W1, b1, bufX);

    // layer 2: agg1 = A_norm h1 (bf16), h2 = relu(agg1 @ W2 + b2) (bf16, MFMA)
    hipLaunchKernelGGL(agg512bf_k, dim3(N), dim3(256), 0, stream, bufX, bufY, offs, ssrc, sw, dis,
                       (const float*)nullptr, 0);
    hipLaunchKernelGGL(mfma_gemm_k, dim3(1024 / 128, (N + 127) / 128), dim3(256), 0, stream,
                       bufY, w2t, b2, bufZ, N, 1024, 512, 1);

    // layer 3: g3 = h2 @ W3 (bf16, MFMA), h3 = relu(A_norm g3 + b3) (bf16)
    hipLaunchKernelGGL(mfma_gemm_k, dim3(512 / 128, (N + 127) / 128), dim3(256), 0, stream,
                       bufZ, w3t, (const float*)nullptr, bufX, N, 512, 1024, 0);
    hipLaunchKernelGGL(agg512bf_k, dim3(N), dim3(256), 0, stream, bufX, bufY, offs, ssrc, sw, dis,
                       b3, 1);

    // mean pool + head (fp32)
    hipLaunchKernelGGL(count_k, dim3(gN), dim3(256), 0, stream, batch, gcnt, N);
    hipLaunchKernelGGL(pool_k, dim3(128), dim3(256), 0, stream, bufY, batch, gsum, N);
    hipLaunchKernelGGL(fc_k, dim3(NGRAPH), dim3(128), 0, stream, gsum, gcnt, fcw1, fcb1, fcw2, fcb2, out);
}

// Round 4
// 741.888 us; speedup vs baseline: 3.8819x; 1.2628x over previous
//
#include <hip/hip_runtime.h>
#include <hip/hip_bf16.h>

#define NNODES 50000
#define NEDGES 400000
#define NGRAPH 16

typedef __attribute__((ext_vector_type(4))) float floatx4;
typedef __attribute__((ext_vector_type(8))) short short8;

// ---------------------------------------------------------------------------
// fallback: write zeros to out (signals "workspace too small" cleanly)
__global__ __launch_bounds__(64) void zero_out_k(float* out, int n) {
    int i = blockIdx.x * 64 + threadIdx.x;
    if (i < n) out[i] = 0.0f;
}

// k0: zero counters / accumulators
__global__ __launch_bounds__(256) void init_k(int* deg_cnt, int* cursor,
                                              float* gsum, int* gcnt, int n) {
    int i = blockIdx.x * 256 + threadIdx.x;
    if (i < n) { deg_cnt[i] = 0; cursor[i] = 0; }
    if (i < NGRAPH * 512) gsum[i] = 0.0f;
    if (i < NGRAPH) gcnt[i] = 0;
}

// k1: in-degree histogram over col
__global__ __launch_bounds__(256) void deg_k(const int* __restrict__ col,
                                             int* __restrict__ deg_cnt, int e) {
    int i = blockIdx.x * 256 + threadIdx.x;
    if (i < e) atomicAdd(&deg_cnt[col[i]], 1);
}

// k2: dis = rsqrt(deg + 1)
__global__ __launch_bounds__(256) void dis_k(const int* __restrict__ deg_cnt,
                                             float* __restrict__ dis, int n) {
    int i = blockIdx.x * 256 + threadIdx.x;
    if (i < n) dis[i] = rsqrtf((float)(deg_cnt[i] + 1));
}

// k3: single-block exclusive scan
__global__ __launch_bounds__(1024) void scan_k(const int* __restrict__ cnt,
                                               int* __restrict__ offs, int n) {
    __shared__ int sbuf[1024];
    int t = threadIdx.x;
    int chunk = (n + 1023) / 1024;
    int beg = t * chunk;
    int end = min(beg + chunk, n);
    int s = 0;
    for (int i = beg; i < end; ++i) s += cnt[i];
    sbuf[t] = s;
    __syncthreads();
    for (int off = 1; off < 1024; off <<= 1) {
        int v = (t >= off) ? sbuf[t - off] : 0;
        __syncthreads();
        sbuf[t] += v;
        __syncthreads();
    }
    int run = sbuf[t] - s;
    for (int i = beg; i < end; ++i) { offs[i] = run; run += cnt[i]; }
    if (t == 1023) offs[n] = sbuf[1023];
}

// k4: scatter edges into dest-keyed CSR; weight = dis[src]
__global__ __launch_bounds__(256) void scatter_k(const int* __restrict__ row,
                                                 const int* __restrict__ col,
                                                 const int* __restrict__ offs,
                                                 int* __restrict__ cursor,
                                                 int* __restrict__ ssrc,
                                                 float* __restrict__ sw,
                                                 const float* __restrict__ dis, int e) {
    int i = blockIdx.x * 256 + threadIdx.x;
    if (i >= e) return;
    int d = col[i];
    int p = offs[d] + atomicAdd(&cursor[d], 1);
    int s = row[i];
    ssrc[p] = s;
    sw[p]   = dis[s];
}

// k5: aggregate x (F=3) fp32
__global__ __launch_bounds__(256) void agg3_k(const float* __restrict__ x,
                                              float* __restrict__ out,
                                              const int* __restrict__ offs,
                                              const int* __restrict__ ssrc,
                                              const float* __restrict__ sw,
                                              const float* __restrict__ dis, int n) {
    int d = blockIdx.x * 256 + threadIdx.x;
    if (d >= n) return;
    float dd = dis[d];
    float a0 = dd * x[d * 3 + 0];
    float a1 = dd * x[d * 3 + 1];
    float a2 = dd * x[d * 3 + 2];
    int beg = offs[d], end = offs[d + 1];
    for (int e = beg; e < end; ++e) {
        int s = ssrc[e];
        float w = sw[e];
        a0 += w * x[s * 3 + 0];
        a1 += w * x[s * 3 + 1];
        a2 += w * x[s * 3 + 2];
    }
    out[d * 3 + 0] = dd * a0;
    out[d * 3 + 1] = dd * a1;
    out[d * 3 + 2] = dd * a2;
}

// k6: h1 = relu(aggx[N,3] @ W1[3,512] + b1) -> bf16
__global__ __launch_bounds__(256) void gemm1_k(const float* __restrict__ aggx,
                                               const float* __restrict__ W1,
                                               const float* __restrict__ b1,
                                               __hip_bfloat16* __restrict__ h1) {
    int d = blockIdx.x;
    int t = threadIdx.x;
    float a0 = aggx[d * 3 + 0], a1 = aggx[d * 3 + 1], a2 = aggx[d * 3 + 2];
    for (int f = t; f < 512; f += 256) {
        float v = b1[f] + a0 * W1[f] + a1 * W1[512 + f] + a2 * W1[1024 + f];
        h1[(size_t)d * 512 + f] = __float2bfloat16(fmaxf(v, 0.0f));
    }
}

__device__ inline float bs2f(short v) {
    return __uint_as_float(((unsigned int)(unsigned short)v) << 16);
}

// k7: aggregation F=512, one WAVE per node, 16B loads (1KB coalesced per row)
__global__ __launch_bounds__(256) void agg512w_k(const __hip_bfloat16* __restrict__ in,
                                                 __hip_bfloat16* __restrict__ out,
                                                 const int* __restrict__ offs,
                                                 const int* __restrict__ ssrc,
                                                 const float* __restrict__ sw,
                                                 const float* __restrict__ dis,
                                                 const float* __restrict__ bias,
                                                 int relu, int n) {
    int wave = threadIdx.x >> 6;
    int lane = threadIdx.x & 63;
    int d = blockIdx.x * 4 + wave;
    if (d >= n) return;
    float dd = dis[d];
    short8 p = *(const short8*)&in[(size_t)d * 512 + lane * 8];
    float acc[8];
#pragma unroll
    for (int j = 0; j < 8; ++j) acc[j] = dd * bs2f(p[j]);

    int beg = offs[d], end = offs[d + 1];
    int e = beg;
    for (; e + 1 < end; e += 2) {
        int s0 = ssrc[e],  s1 = ssrc[e + 1];
        float w0 = sw[e],  w1 = sw[e + 1];
        short8 q0 = *(const short8*)&in[(size_t)s0 * 512 + lane * 8];
        short8 q1 = *(const short8*)&in[(size_t)s1 * 512 + lane * 8];
#pragma unroll
        for (int j = 0; j < 8; ++j) acc[j] += w0 * bs2f(q0[j]);
#pragma unroll
        for (int j = 0; j < 8; ++j) acc[j] += w1 * bs2f(q1[j]);
    }
    if (e < end) {
        int s0 = ssrc[e];
        float w0 = sw[e];
        short8 q0 = *(const short8*)&in[(size_t)s0 * 512 + lane * 8];
#pragma unroll
        for (int j = 0; j < 8; ++j) acc[j] += w0 * bs2f(q0[j]);
    }

    short8 ov;
#pragma unroll
    for (int j = 0; j < 8; ++j) {
        float v = acc[j] * dd;
        if (bias) v += bias[lane * 8 + j];
        if (relu) v = fmaxf(v, 0.0f);
        __hip_bfloat16 h = __float2bfloat16(v);
        ov[j] = *(short*)&h;
    }
    *(short8*)&out[(size_t)d * 512 + lane * 8] = ov;
}

// k-tc: tiled transpose + f32->bf16 convert: W[K][N] -> Wt[N][K]
__global__ __launch_bounds__(256) void tcvt_k(const float* __restrict__ W,
                                              __hip_bfloat16* __restrict__ Wt,
                                              int K, int N) {
    __shared__ float tile[32][33];
    int t = threadIdx.x;
    int bn = blockIdx.x * 32;   // n
    int bk = blockIdx.y * 32;   // k
    int c = t & 31, r0 = t >> 5;
#pragma unroll
    for (int j = 0; j < 4; ++j) {
        int r = r0 + j * 8;
        tile[r][c] = W[(size_t)(bk + r) * N + bn + c];
    }
    __syncthreads();
#pragma unroll
    for (int j = 0; j < 4; ++j) {
        int r = r0 + j * 8;
        Wt[(size_t)(bn + r) * K + bk + c] = __float2bfloat16(tile[c][r]);
    }
}

// k8: bf16 MFMA GEMM: C[M,N] = epi(A[M,K] @ Bt[N,K]^T + bias)
// 128x128 tile, BK=32, 256 thr = 4 waves (2x2), 16x16x32 MFMA.
#define LSTR 40   // LDS row stride in bf16 elems (32 + 8 pad)
__global__ __launch_bounds__(256) void mfma_gemm_k(const __hip_bfloat16* __restrict__ A,
                                                   const __hip_bfloat16* __restrict__ Bt,
                                                   const float* __restrict__ bias,
                                                   __hip_bfloat16* __restrict__ C,
                                                   int M, int N, int K, int relu) {
    __shared__ short smem[17408];          // staging (2*5120) / epi (128*136)
    short* As = smem;                      // [128][LSTR]
    short* Bs = smem + 128 * LSTR;         // [128][LSTR]
    short* Cs = smem;                      // [128][136] (epilogue reuse)

    int tid  = threadIdx.x;
    int lane = tid & 63;
    int wave = tid >> 6;
    int wm = (wave >> 1) * 64;
    int wn = (wave & 1) * 64;
    int fr = lane & 15;
    int kg = lane >> 4;

    int bm = blockIdx.y * 128;
    int bn = blockIdx.x * 128;

    floatx4 acc[4][4] = {};

    for (int k0 = 0; k0 < K; k0 += 32) {
#pragma unroll
        for (int i = 0; i < 2; ++i) {
            int c  = tid + 256 * i;
            int r  = c >> 2;
            int cc = c & 3;
            short8 av = {};
            int garow = bm + r;
            if (garow < M) av = *(const short8*)&A[(size_t)garow * K + k0 + cc * 8];
            *(short8*)&As[r * LSTR + cc * 8] = av;
            *(short8*)&Bs[r * LSTR + cc * 8] =
                *(const short8*)&Bt[(size_t)(bn + r) * K + k0 + cc * 8];
        }
        __syncthreads();

        short8 af[4], bf[4];
#pragma unroll
        for (int mi = 0; mi < 4; ++mi)
            af[mi] = *(short8*)&As[(wm + mi * 16 + fr) * LSTR + kg * 8];
#pragma unroll
        for (int ni = 0; ni < 4; ++ni)
            bf[ni] = *(short8*)&Bs[(wn + ni * 16 + fr) * LSTR + kg * 8];
#pragma unroll
        for (int mi = 0; mi < 4; ++mi)
#pragma unroll
            for (int ni = 0; ni < 4; ++ni)
                acc[mi][ni] = __builtin_amdgcn_mfma_f32_16x16x32_bf16(
                    af[mi], bf[ni], acc[mi][ni], 0, 0, 0);
        __syncthreads();
    }

#pragma unroll
    for (int mi = 0; mi < 4; ++mi) {
#pragma unroll
        for (int ni = 0; ni < 4; ++ni) {
            int rl = wm + mi * 16 + (lane >> 4) * 4;
            int cl = wn + ni * 16 + (lane & 15);
            float bv = bias ? bias[bn + cl] : 0.0f;
#pragma unroll
            for (int r = 0; r < 4; ++r) {
                float v = acc[mi][ni][r] + bv;
                if (relu) v = fmaxf(v, 0.0f);
                __hip_bfloat16 h = __float2bfloat16(v);
                Cs[(rl + r) * 136 + cl] = *(short*)&h;
            }
        }
    }
    __syncthreads();
#pragma unroll
    for (int i = 0; i < 8; ++i) {
        int c  = tid + 256 * i;
        int rr = c >> 4;
        int cc = c & 15;
        int grow = bm + rr;
        if (grow < M)
            *(short8*)&C[(size_t)grow * N + bn + cc * 8] =
                *(short8*)&Cs[rr * 136 + cc * 8];
    }
}

// k9: per-graph node counts — LDS histogram, 16 global atomics per block
__global__ __launch_bounds__(256) void count_k(const int* __restrict__ batch,
                                               int* __restrict__ gcnt, int n) {
    __shared__ int h[NGRAPH];
    int t = threadIdx.x;
    if (t < NGRAPH) h[t] = 0;
    __syncthreads();
    for (int i = blockIdx.x * 256 + t; i < n; i += gridDim.x * 256)
        atomicAdd(&h[batch[i]], 1);
    __syncthreads();
    if (t < NGRAPH) atomicAdd(&gcnt[t], h[t]);
}

// k10: pooled sums, bf16 input, LDS fp32 accumulators
__global__ __launch_bounds__(256) void pool_k(const __hip_bfloat16* __restrict__ h,
                                              const int* __restrict__ batch,
                                              float* __restrict__ gsum, int n) {
    __shared__ float ls[NGRAPH * 512];
    int t = threadIdx.x;
    for (int i = t; i < NGRAPH * 512; i += 256) ls[i] = 0.0f;
    __syncthreads();
    for (int d = blockIdx.x; d < n; d += gridDim.x) {
        int g = batch[d];
        unsigned int q = *(const unsigned int*)&h[(size_t)d * 512 + 2 * t];
        ls[g * 512 + 2 * t]     += __uint_as_float((q & 0xffffu) << 16);
        ls[g * 512 + 2 * t + 1] += __uint_as_float((q >> 16) << 16);
    }
    __syncthreads();
    for (int i = t; i < NGRAPH * 512; i += 256) atomicAdd(&gsum[i], ls[i]);
}

// k11: head MLP (fp32)
__global__ __launch_bounds__(128) void fc_k(const float* __restrict__ gsum,
                                            const int* __restrict__ gcnt,
                                            const float* __restrict__ fcw1,
                                            const float* __restrict__ fcb1,
                                            const float* __restrict__ fcw2,
                                            const float* __restrict__ fcb2,
                                            float* __restrict__ out) {
    int g = blockIdx.x;
    int t = threadIdx.x;  // 128
    __shared__ float pooled[512];
    __shared__ float red[128];
    float inv = 1.0f / fmaxf((float)gcnt[g], 1.0f);
    for (int i = t; i < 512; i += 128) pooled[i] = gsum[g * 512 + i] * inv;
    __syncthreads();
    float s = fcb1[t];
    for (int k = 0; k < 512; ++k) s += pooled[k] * fcw1[k * 128 + t];
    s = fmaxf(s, 0.0f);
    red[t] = s * fcw2[t];
    __syncthreads();
    for (int off = 64; off > 0; off >>= 1) {
        if (t < off) red[t] += red[t + off];
        __syncthreads();
    }
    if (t == 0) out[g] = red[0] + fcb2[0];
}

extern "C" void kernel_launch(void* const* d_in, const int* in_sizes, int n_in,
                              void* d_out, int out_size, void* d_ws, size_t ws_size,
                              hipStream_t stream) {
    const float* x    = (const float*)d_in[0];
    const int*   ei   = (const int*)d_in[1];   // [2, E]
    const int*   batch= (const int*)d_in[2];
    const float* W1   = (const float*)d_in[3];
    const float* b1   = (const float*)d_in[4];
    const float* W2   = (const float*)d_in[5];
    const float* b2   = (const float*)d_in[6];
    const float* W3   = (const float*)d_in[7];
    const float* b3   = (const float*)d_in[8];
    const float* fcw1 = (const float*)d_in[9];
    const float* fcb1 = (const float*)d_in[10];
    const float* fcw2 = (const float*)d_in[11];
    const float* fcb2 = (const float*)d_in[12];
    float* out = (float*)d_out;

    const int N = in_sizes[0] / 3;      // 50000
    const int E = in_sizes[1] / 2;      // 400000
    const int* row = ei;
    const int* col = ei + E;

    // ---- workspace layout ----
    size_t used = 0;
    auto need = [&](size_t bytes) {
        size_t off = used;
        used += (bytes + 255) & ~(size_t)255;
        return off;
    };
    size_t o_deg  = need((size_t)N * 4);
    size_t o_cur  = need((size_t)N * 4);
    size_t o_dis  = need((size_t)N * 4);
    size_t o_offs = need((size_t)(N + 1) * 4);
    size_t o_ssrc = need((size_t)E * 4);
    size_t o_sw   = need((size_t)E * 4);
    size_t o_aggx = need((size_t)N * 3 * 4);
    size_t o_gsum = need((size_t)NGRAPH * 512 * 4);
    size_t o_gcnt = need((size_t)NGRAPH * 4);
    size_t o_w2t  = need((size_t)512 * 1024 * 2);   // W2^T bf16 [1024][512]
    size_t o_w3t  = need((size_t)1024 * 512 * 2);   // W3^T bf16 [512][1024]
    size_t o_bufX = need((size_t)N * 512 * 2);      // h1 -> g3   (bf16)
    size_t o_bufY = need((size_t)N * 512 * 2);      // agg1 -> h3 (bf16)
    size_t o_bufZ = need((size_t)N * 1024 * 2);     // h2         (bf16)

    if (used > ws_size) {
        hipLaunchKernelGGL(zero_out_k, dim3((out_size + 63) / 64), dim3(64), 0, stream,
                           out, out_size);
        return;
    }

    char* base = (char*)d_ws;
    int*   deg_cnt = (int*)  (base + o_deg);
    int*   cursor  = (int*)  (base + o_cur);
    float* dis     = (float*)(base + o_dis);
    int*   offs    = (int*)  (base + o_offs);
    int*   ssrc    = (int*)  (base + o_ssrc);
    float* sw      = (float*)(base + o_sw);
    float* aggx    = (float*)(base + o_aggx);
    float* gsum    = (float*)(base + o_gsum);
    int*   gcnt    = (int*)  (base + o_gcnt);
    __hip_bfloat16* w2t  = (__hip_bfloat16*)(base + o_w2t);
    __hip_bfloat16* w3t  = (__hip_bfloat16*)(base + o_w3t);
    __hip_bfloat16* bufX = (__hip_bfloat16*)(base + o_bufX);
    __hip_bfloat16* bufY = (__hip_bfloat16*)(base + o_bufY);
    __hip_bfloat16* bufZ = (__hip_bfloat16*)(base + o_bufZ);
    (void)n_in;

    int gN = (N + 255) / 256;
    int gE = (E + 255) / 256;
    int gW = (N + 3) / 4;   // wave-per-node grids

    // CSR build + norm
    hipLaunchKernelGGL(init_k, dim3(gN), dim3(256), 0, stream, deg_cnt, cursor, gsum, gcnt, N);
    hipLaunchKernelGGL(deg_k, dim3(gE), dim3(256), 0, stream, col, deg_cnt, E);
    hipLaunchKernelGGL(dis_k, dim3(gN), dim3(256), 0, stream, deg_cnt, dis, N);
    hipLaunchKernelGGL(scan_k, dim3(1), dim3(1024), 0, stream, deg_cnt, offs, N);
    hipLaunchKernelGGL(scatter_k, dim3(gE), dim3(256), 0, stream, row, col, offs, cursor, ssrc, sw, dis, E);

    // weights: transpose + bf16 convert
    hipLaunchKernelGGL(tcvt_k, dim3(1024 / 32, 512 / 32), dim3(256), 0, stream, W2, w2t, 512, 1024);
    hipLaunchKernelGGL(tcvt_k, dim3(512 / 32, 1024 / 32), dim3(256), 0, stream, W3, w3t, 1024, 512);

    // layer 1: agg(F=3) fp32, then 3->512 GEMM -> h1 bf16
    hipLaunchKernelGGL(agg3_k, dim3(gN), dim3(256), 0, stream, x, aggx, offs, ssrc, sw, dis, N);
    hipLaunchKernelGGL(gemm1_k, dim3(N), dim3(256), 0, stream, aggx, W1, b1, bufX);

    // layer 2: agg1 = A_norm h1, h2 = relu(agg1 @ W2 + b2)
    hipLaunchKernelGGL(agg512w_k, dim3(gW), dim3(256), 0, stream, bufX, bufY, offs, ssrc, sw, dis,
                       (const float*)nullptr, 0, N);
    hipLaunchKernelGGL(mfma_gemm_k, dim3(1024 / 128, (N + 127) / 128), dim3(256), 0, stream,
                       bufY, w2t, b2, bufZ, N, 1024, 512, 1);

    // layer 3: g3 = h2 @ W3, h3 = relu(A_norm g3 + b3)
    hipLaunchKernelGGL(mfma_gemm_k, dim3(512 / 128, (N + 127) / 128), dim3(256), 0, stream,
                       bufZ, w3t, (const float*)nullptr, bufX, N, 512, 1024, 0);
    hipLaunchKernelGGL(agg512w_k, dim3(gW), dim3(256), 0, stream, bufX, bufY, offs, ssrc, sw, dis,
                       b3, 1, N);

    // mean pool + head
    hipLaunchKernelGGL(count_k, dim3(64), dim3(256), 0, stream, batch, gcnt, N);
    hipLaunchKernelGGL(pool_k, dim3(128), dim3(256), 0, stream, bufY, batch, gsum, N);
    hipLaunchKernelGGL(fc_k, dim3(NGRAPH), dim3(128), 0, stream, gsum, gcnt, fcw1, fcb1, fcw2, fcb2, out);
}

// Round 5
// 728.919 us; speedup vs baseline: 3.9509x; 1.0178x over previous
//
#include <hip/hip_runtime.h>
#include <hip/hip_bf16.h>

#define NNODES 50000
#define NEDGES 400000
#define NGRAPH 16

typedef __attribute__((ext_vector_type(4))) float floatx4;
typedef __attribute__((ext_vector_type(8))) short short8;

typedef __attribute__((address_space(3))) unsigned int lds_uint;
typedef __attribute__((address_space(1))) const unsigned int gbl_uint;

__device__ __forceinline__ void load16_to_lds(const void* g, void* l) {
    __builtin_amdgcn_global_load_lds((gbl_uint*)g, (lds_uint*)l, 16, 0, 0);
}

// ---------------------------------------------------------------------------
// fallback: write zeros to out (signals "workspace too small" cleanly)
__global__ __launch_bounds__(64) void zero_out_k(float* out, int n) {
    int i = blockIdx.x * 64 + threadIdx.x;
    if (i < n) out[i] = 0.0f;
}

// k0: zero counters / accumulators
__global__ __launch_bounds__(256) void init_k(int* deg_cnt, int* cursor,
                                              float* gsum, int* gcnt, int n) {
    int i = blockIdx.x * 256 + threadIdx.x;
    if (i < n) { deg_cnt[i] = 0; cursor[i] = 0; }
    if (i < NGRAPH * 512) gsum[i] = 0.0f;
    if (i < NGRAPH) gcnt[i] = 0;
}

// k1: in-degree histogram over col
__global__ __launch_bounds__(256) void deg_k(const int* __restrict__ col,
                                             int* __restrict__ deg_cnt, int e) {
    int i = blockIdx.x * 256 + threadIdx.x;
    if (i < e) atomicAdd(&deg_cnt[col[i]], 1);
}

// k2: dis = rsqrt(deg + 1)
__global__ __launch_bounds__(256) void dis_k(const int* __restrict__ deg_cnt,
                                             float* __restrict__ dis, int n) {
    int i = blockIdx.x * 256 + threadIdx.x;
    if (i < n) dis[i] = rsqrtf((float)(deg_cnt[i] + 1));
}

// k3: single-block exclusive scan
__global__ __launch_bounds__(1024) void scan_k(const int* __restrict__ cnt,
                                               int* __restrict__ offs, int n) {
    __shared__ int sbuf[1024];
    int t = threadIdx.x;
    int chunk = (n + 1023) / 1024;
    int beg = t * chunk;
    int end = min(beg + chunk, n);
    int s = 0;
    for (int i = beg; i < end; ++i) s += cnt[i];
    sbuf[t] = s;
    __syncthreads();
    for (int off = 1; off < 1024; off <<= 1) {
        int v = (t >= off) ? sbuf[t - off] : 0;
        __syncthreads();
        sbuf[t] += v;
        __syncthreads();
    }
    int run = sbuf[t] - s;
    for (int i = beg; i < end; ++i) { offs[i] = run; run += cnt[i]; }
    if (t == 1023) offs[n] = sbuf[1023];
}

// k4: scatter edges into dest-keyed CSR; weight = dis[src]
__global__ __launch_bounds__(256) void scatter_k(const int* __restrict__ row,
                                                 const int* __restrict__ col,
                                                 const int* __restrict__ offs,
                                                 int* __restrict__ cursor,
                                                 int* __restrict__ ssrc,
                                                 float* __restrict__ sw,
                                                 const float* __restrict__ dis, int e) {
    int i = blockIdx.x * 256 + threadIdx.x;
    if (i >= e) return;
    int d = col[i];
    int p = offs[d] + atomicAdd(&cursor[d], 1);
    int s = row[i];
    ssrc[p] = s;
    sw[p]   = dis[s];
}

// k5: aggregate x (F=3) fp32
__global__ __launch_bounds__(256) void agg3_k(const float* __restrict__ x,
                                              float* __restrict__ out,
                                              const int* __restrict__ offs,
                                              const int* __restrict__ ssrc,
                                              const float* __restrict__ sw,
                                              const float* __restrict__ dis, int n) {
    int d = blockIdx.x * 256 + threadIdx.x;
    if (d >= n) return;
    float dd = dis[d];
    float a0 = dd * x[d * 3 + 0];
    float a1 = dd * x[d * 3 + 1];
    float a2 = dd * x[d * 3 + 2];
    int beg = offs[d], end = offs[d + 1];
    for (int e = beg; e < end; ++e) {
        int s = ssrc[e];
        float w = sw[e];
        a0 += w * x[s * 3 + 0];
        a1 += w * x[s * 3 + 1];
        a2 += w * x[s * 3 + 2];
    }
    out[d * 3 + 0] = dd * a0;
    out[d * 3 + 1] = dd * a1;
    out[d * 3 + 2] = dd * a2;
}

// k6: h1 = relu(aggx[N,3] @ W1[3,512] + b1) -> bf16
__global__ __launch_bounds__(256) void gemm1_k(const float* __restrict__ aggx,
                                               const float* __restrict__ W1,
                                               const float* __restrict__ b1,
                                               __hip_bfloat16* __restrict__ h1) {
    int d = blockIdx.x;
    int t = threadIdx.x;
    float a0 = aggx[d * 3 + 0], a1 = aggx[d * 3 + 1], a2 = aggx[d * 3 + 2];
    for (int f = t; f < 512; f += 256) {
        float v = b1[f] + a0 * W1[f] + a1 * W1[512 + f] + a2 * W1[1024 + f];
        h1[(size_t)d * 512 + f] = __float2bfloat16(fmaxf(v, 0.0f));
    }
}

__device__ inline float bs2f(short v) {
    return __uint_as_float(((unsigned int)(unsigned short)v) << 16);
}

// k7: aggregation F=512, one WAVE per node, 16B loads, edge loop unrolled x4
__global__ __launch_bounds__(256) void agg512w_k(const __hip_bfloat16* __restrict__ in,
                                                 __hip_bfloat16* __restrict__ out,
                                                 const int* __restrict__ offs,
                                                 const int* __restrict__ ssrc,
                                                 const float* __restrict__ sw,
                                                 const float* __restrict__ dis,
                                                 const float* __restrict__ bias,
                                                 int relu, int n) {
    int wave = threadIdx.x >> 6;
    int lane = threadIdx.x & 63;
    int d = blockIdx.x * 4 + wave;
    if (d >= n) return;
    float dd = dis[d];
    short8 p = *(const short8*)&in[(size_t)d * 512 + lane * 8];
    float acc[8];
#pragma unroll
    for (int j = 0; j < 8; ++j) acc[j] = dd * bs2f(p[j]);

    int beg = offs[d], end = offs[d + 1];
    int e = beg;
    for (; e + 3 < end; e += 4) {
        int s0 = ssrc[e],     s1 = ssrc[e + 1];
        int s2 = ssrc[e + 2], s3 = ssrc[e + 3];
        float w0 = sw[e],     w1 = sw[e + 1];
        float w2 = sw[e + 2], w3 = sw[e + 3];
        short8 q0 = *(const short8*)&in[(size_t)s0 * 512 + lane * 8];
        short8 q1 = *(const short8*)&in[(size_t)s1 * 512 + lane * 8];
        short8 q2 = *(const short8*)&in[(size_t)s2 * 512 + lane * 8];
        short8 q3 = *(const short8*)&in[(size_t)s3 * 512 + lane * 8];
#pragma unroll
        for (int j = 0; j < 8; ++j) acc[j] += w0 * bs2f(q0[j]);
#pragma unroll
        for (int j = 0; j < 8; ++j) acc[j] += w1 * bs2f(q1[j]);
#pragma unroll
        for (int j = 0; j < 8; ++j) acc[j] += w2 * bs2f(q2[j]);
#pragma unroll
        for (int j = 0; j < 8; ++j) acc[j] += w3 * bs2f(q3[j]);
    }
    for (; e < end; ++e) {
        int s0 = ssrc[e];
        float w0 = sw[e];
        short8 q0 = *(const short8*)&in[(size_t)s0 * 512 + lane * 8];
#pragma unroll
        for (int j = 0; j < 8; ++j) acc[j] += w0 * bs2f(q0[j]);
    }

    short8 ov;
#pragma unroll
    for (int j = 0; j < 8; ++j) {
        float v = acc[j] * dd;
        if (bias) v += bias[lane * 8 + j];
        if (relu) v = fmaxf(v, 0.0f);
        __hip_bfloat16 h = __float2bfloat16(v);
        ov[j] = *(short*)&h;
    }
    *(short8*)&out[(size_t)d * 512 + lane * 8] = ov;
}

// k-tc: tiled transpose + f32->bf16 convert: W[K][N] -> Wt[N][K]
__global__ __launch_bounds__(256) void tcvt_k(const float* __restrict__ W,
                                              __hip_bfloat16* __restrict__ Wt,
                                              int K, int N) {
    __shared__ float tile[32][33];
    int t = threadIdx.x;
    int bn = blockIdx.x * 32;
    int bk = blockIdx.y * 32;
    int c = t & 31, r0 = t >> 5;
#pragma unroll
    for (int j = 0; j < 4; ++j) {
        int r = r0 + j * 8;
        tile[r][c] = W[(size_t)(bk + r) * N + bn + c];
    }
    __syncthreads();
#pragma unroll
    for (int j = 0; j < 4; ++j) {
        int r = r0 + j * 8;
        Wt[(size_t)(bn + r) * K + bk + c] = __float2bfloat16(tile[c][r]);
    }
}

// k8: bf16 MFMA GEMM, m97-style: C[M,N] = epi(A[M,K] @ Bt[N,K]^T + bias)
// 128x128 tile, BK=32, 4 waves (2x2, each 64x64 via 4x4 16x16x32 MFMA).
// Staging via global_load_lds width=16 directly into FRAGMENT-MAJOR LDS:
//   segment s (1KB) = 16x32 fragment block; lane kg*16+fr fetches
//   row fr, k-chunk kg -> lands at seg_base + lane*16. Fragment ds_read_b128
//   is then seg_base + lane*16: conflict-free by construction.
// Segments 0..7 = A (rows bm..bm+127), 8..15 = B (rows bn..bn+127).
// M-edge: row index clamped to M-1 (garbage flows only to unstored C rows).
// Requires: K%32==0, N%128==0, 16B-aligned A/Bt.
__global__ __launch_bounds__(256) void mfma_gemm_k(const __hip_bfloat16* __restrict__ A,
                                                   const __hip_bfloat16* __restrict__ Bt,
                                                   const float* __restrict__ bias,
                                                   __hip_bfloat16* __restrict__ C,
                                                   int M, int N, int K, int relu) {
    __shared__ short smem[17408];   // staging 16x512 shorts (16KB) / epi 128x136

    int tid  = threadIdx.x;
    int lane = tid & 63;
    int wave = tid >> 6;
    int wm = (wave >> 1) * 64;
    int wn = (wave & 1) * 64;
    int fr = lane & 15;
    int kg = lane >> 4;

    int bm = blockIdx.y * 128;
    int bn = blockIdx.x * 128;

    // per-thread global source pointers for this wave's 4 staging segments
    const __hip_bfloat16* gsrc[4];
#pragma unroll
    for (int i = 0; i < 4; ++i) {
        int s = wave * 4 + i;
        if (s < 8) {
            int g = bm + s * 16 + fr;
            g = min(g, M - 1);
            gsrc[i] = A + (size_t)g * K + kg * 8;
        } else {
            int g = bn + (s - 8) * 16 + fr;
            gsrc[i] = Bt + (size_t)g * K + kg * 8;
        }
    }

    floatx4 acc[4][4] = {};

    for (int k0 = 0; k0 < K; k0 += 32) {
#pragma unroll
        for (int i = 0; i < 4; ++i) {
            int s = wave * 4 + i;
            load16_to_lds(gsrc[i], &smem[s * 512]);
            gsrc[i] += 32;
        }
        __syncthreads();   // drains vmcnt (incl. lds-direct loads) + barrier

        short8 af[4], bf[4];
#pragma unroll
        for (int mi = 0; mi < 4; ++mi)
            af[mi] = *(short8*)&smem[((wm >> 4) + mi) * 512 + lane * 8];
#pragma unroll
        for (int ni = 0; ni < 4; ++ni)
            bf[ni] = *(short8*)&smem[(8 + (wn >> 4) + ni) * 512 + lane * 8];
#pragma unroll
        for (int mi = 0; mi < 4; ++mi)
#pragma unroll
            for (int ni = 0; ni < 4; ++ni)
                acc[mi][ni] = __builtin_amdgcn_mfma_f32_16x16x32_bf16(
                    af[mi], bf[ni], acc[mi][ni], 0, 0, 0);
        __syncthreads();
    }

    // epilogue: bias+relu, repack via LDS, coalesced 16B stores
    short* Cs = smem;   // [128][136]
#pragma unroll
    for (int mi = 0; mi < 4; ++mi) {
#pragma unroll
        for (int ni = 0; ni < 4; ++ni) {
            int rl = wm + mi * 16 + (lane >> 4) * 4;
            int cl = wn + ni * 16 + (lane & 15);
            float bv = bias ? bias[bn + cl] : 0.0f;
#pragma unroll
            for (int r = 0; r < 4; ++r) {
                float v = acc[mi][ni][r] + bv;
                if (relu) v = fmaxf(v, 0.0f);
                __hip_bfloat16 h = __float2bfloat16(v);
                Cs[(rl + r) * 136 + cl] = *(short*)&h;
            }
        }
    }
    __syncthreads();
#pragma unroll
    for (int i = 0; i < 8; ++i) {
        int c  = tid + 256 * i;
        int rr = c >> 4;
        int cc = c & 15;
        int grow = bm + rr;
        if (grow < M)
            *(short8*)&C[(size_t)grow * N + bn + cc * 8] =
                *(short8*)&Cs[rr * 136 + cc * 8];
    }
}

// k9: per-graph node counts — LDS histogram
__global__ __launch_bounds__(256) void count_k(const int* __restrict__ batch,
                                               int* __restrict__ gcnt, int n) {
    __shared__ int h[NGRAPH];
    int t = threadIdx.x;
    if (t < NGRAPH) h[t] = 0;
    __syncthreads();
    for (int i = blockIdx.x * 256 + t; i < n; i += gridDim.x * 256)
        atomicAdd(&h[batch[i]], 1);
    __syncthreads();
    if (t < NGRAPH) atomicAdd(&gcnt[t], h[t]);
}

// k10: pooled sums, bf16 input, LDS fp32 accumulators
__global__ __launch_bounds__(256) void pool_k(const __hip_bfloat16* __restrict__ h,
                                              const int* __restrict__ batch,
                                              float* __restrict__ gsum, int n) {
    __shared__ float ls[NGRAPH * 512];
    int t = threadIdx.x;
    for (int i = t; i < NGRAPH * 512; i += 256) ls[i] = 0.0f;
    __syncthreads();
    for (int d = blockIdx.x; d < n; d += gridDim.x) {
        int g = batch[d];
        unsigned int q = *(const unsigned int*)&h[(size_t)d * 512 + 2 * t];
        ls[g * 512 + 2 * t]     += __uint_as_float((q & 0xffffu) << 16);
        ls[g * 512 + 2 * t + 1] += __uint_as_float((q >> 16) << 16);
    }
    __syncthreads();
    for (int i = t; i < NGRAPH * 512; i += 256) atomicAdd(&gsum[i], ls[i]);
}

// k11: head MLP (fp32)
__global__ __launch_bounds__(128) void fc_k(const float* __restrict__ gsum,
                                            const int* __restrict__ gcnt,
                                            const float* __restrict__ fcw1,
                                            const float* __restrict__ fcb1,
                                            const float* __restrict__ fcw2,
                                            const float* __restrict__ fcb2,
                                            float* __restrict__ out) {
    int g = blockIdx.x;
    int t = threadIdx.x;  // 128
    __shared__ float pooled[512];
    __shared__ float red[128];
    float inv = 1.0f / fmaxf((float)gcnt[g], 1.0f);
    for (int i = t; i < 512; i += 128) pooled[i] = gsum[g * 512 + i] * inv;
    __syncthreads();
    float s = fcb1[t];
    for (int k = 0; k < 512; ++k) s += pooled[k] * fcw1[k * 128 + t];
    s = fmaxf(s, 0.0f);
    red[t] = s * fcw2[t];
    __syncthreads();
    for (int off = 64; off > 0; off >>= 1) {
        if (t < off) red[t] += red[t + off];
        __syncthreads();
    }
    if (t == 0) out[g] = red[0] + fcb2[0];
}

extern "C" void kernel_launch(void* const* d_in, const int* in_sizes, int n_in,
                              void* d_out, int out_size, void* d_ws, size_t ws_size,
                              hipStream_t stream) {
    const float* x    = (const float*)d_in[0];
    const int*   ei   = (const int*)d_in[1];   // [2, E]
    const int*   batch= (const int*)d_in[2];
    const float* W1   = (const float*)d_in[3];
    const float* b1   = (const float*)d_in[4];
    const float* W2   = (const float*)d_in[5];
    const float* b2   = (const float*)d_in[6];
    const float* W3   = (const float*)d_in[7];
    const float* b3   = (const float*)d_in[8];
    const float* fcw1 = (const float*)d_in[9];
    const float* fcb1 = (const float*)d_in[10];
    const float* fcw2 = (const float*)d_in[11];
    const float* fcb2 = (const float*)d_in[12];
    float* out = (float*)d_out;

    const int N = in_sizes[0] / 3;      // 50000
    const int E = in_sizes[1] / 2;      // 400000
    const int* row = ei;
    const int* col = ei + E;

    // ---- workspace layout ----
    size_t used = 0;
    auto need = [&](size_t bytes) {
        size_t off = used;
        used += (bytes + 255) & ~(size_t)255;
        return off;
    };
    size_t o_deg  = need((size_t)N * 4);
    size_t o_cur  = need((size_t)N * 4);
    size_t o_dis  = need((size_t)N * 4);
    size_t o_offs = need((size_t)(N + 1) * 4);
    size_t o_ssrc = need((size_t)E * 4);
    size_t o_sw   = need((size_t)E * 4);
    size_t o_aggx = need((size_t)N * 3 * 4);
    size_t o_gsum = need((size_t)NGRAPH * 512 * 4);
    size_t o_gcnt = need((size_t)NGRAPH * 4);
    size_t o_w2t  = need((size_t)512 * 1024 * 2);   // W2^T bf16 [1024][512]
    size_t o_w3t  = need((size_t)1024 * 512 * 2);   // W3^T bf16 [512][1024]
    size_t o_bufX = need((size_t)N * 512 * 2);      // h1 -> g3   (bf16)
    size_t o_bufY = need((size_t)N * 512 * 2);      // agg1 -> h3 (bf16)
    size_t o_bufZ = need((size_t)N * 1024 * 2);     // h2         (bf16)

    if (used > ws_size) {
        hipLaunchKernelGGL(zero_out_k, dim3((out_size + 63) / 64), dim3(64), 0, stream,
                           out, out_size);
        return;
    }

    char* base = (char*)d_ws;
    int*   deg_cnt = (int*)  (base + o_deg);
    int*   cursor  = (int*)  (base + o_cur);
    float* dis     = (float*)(base + o_dis);
    int*   offs    = (int*)  (base + o_offs);
    int*   ssrc    = (int*)  (base + o_ssrc);
    float* sw      = (float*)(base + o_sw);
    float* aggx    = (float*)(base + o_aggx);
    float* gsum    = (float*)(base + o_gsum);
    int*   gcnt    = (int*)  (base + o_gcnt);
    __hip_bfloat16* w2t  = (__hip_bfloat16*)(base + o_w2t);
    __hip_bfloat16* w3t  = (__hip_bfloat16*)(base + o_w3t);
    __hip_bfloat16* bufX = (__hip_bfloat16*)(base + o_bufX);
    __hip_bfloat16* bufY = (__hip_bfloat16*)(base + o_bufY);
    __hip_bfloat16* bufZ = (__hip_bfloat16*)(base + o_bufZ);
    (void)n_in;

    int gN = (N + 255) / 256;
    int gE = (E + 255) / 256;
    int gW = (N + 3) / 4;   // wave-per-node grids

    // CSR build + norm
    hipLaunchKernelGGL(init_k, dim3(gN), dim3(256), 0, stream, deg_cnt, cursor, gsum, gcnt, N);
    hipLaunchKernelGGL(deg_k, dim3(gE), dim3(256), 0, stream, col, deg_cnt, E);
    hipLaunchKernelGGL(dis_k, dim3(gN), dim3(256), 0, stream, deg_cnt, dis, N);
    hipLaunchKernelGGL(scan_k, dim3(1), dim3(1024), 0, stream, deg_cnt, offs, N);
    hipLaunchKernelGGL(scatter_k, dim3(gE), dim3(256), 0, stream, row, col, offs, cursor, ssrc, sw, dis, E);

    // weights: transpose + bf16 convert
    hipLaunchKernelGGL(tcvt_k, dim3(1024 / 32, 512 / 32), dim3(256), 0, stream, W2, w2t, 512, 1024);
    hipLaunchKernelGGL(tcvt_k, dim3(512 / 32, 1024 / 32), dim3(256), 0, stream, W3, w3t, 1024, 512);

    // layer 1: agg(F=3) fp32, then 3->512 GEMM -> h1 bf16
    hipLaunchKernelGGL(agg3_k, dim3(gN), dim3(256), 0, stream, x, aggx, offs, ssrc, sw, dis, N);
    hipLaunchKernelGGL(gemm1_k, dim3(N), dim3(256), 0, stream, aggx, W1, b1, bufX);

    // layer 2: agg1 = A_norm h1, h2 = relu(agg1 @ W2 + b2)
    hipLaunchKernelGGL(agg512w_k, dim3(gW), dim3(256), 0, stream, bufX, bufY, offs, ssrc, sw, dis,
                       (const float*)nullptr, 0, N);
    hipLaunchKernelGGL(mfma_gemm_k, dim3(1024 / 128, (N + 127) / 128), dim3(256), 0, stream,
                       bufY, w2t, b2, bufZ, N, 1024, 512, 1);

    // layer 3: g3 = h2 @ W3, h3 = relu(A_norm g3 + b3)
    hipLaunchKernelGGL(mfma_gemm_k, dim3(512 / 128, (N + 127) / 128), dim3(256), 0, stream,
                       bufZ, w3t, (const float*)nullptr, bufX, N, 512, 1024, 0);
    hipLaunchKernelGGL(agg512w_k, dim3(gW), dim3(256), 0, stream, bufX, bufY, offs, ssrc, sw, dis,
                       b3, 1, N);

    // mean pool + head
    hipLaunchKernelGGL(count_k, dim3(64), dim3(256), 0, stream, batch, gcnt, N);
    hipLaunchKernelGGL(pool_k, dim3(256), dim3(256), 0, stream, bufY, batch, gsum, N);
    hipLaunchKernelGGL(fc_k, dim3(NGRAPH), dim3(128), 0, stream, gsum, gcnt, fcw1, fcb1, fcw2, fcb2, out);
}

// Round 6
// 700.972 us; speedup vs baseline: 4.1084x; 1.0399x over previous
//
#include <hip/hip_runtime.h>
#include <hip/hip_bf16.h>

#define NNODES 50000
#define NEDGES 400000
#define NGRAPH 16

typedef __attribute__((ext_vector_type(4))) float floatx4;
typedef __attribute__((ext_vector_type(8))) short short8;

typedef __attribute__((address_space(3))) unsigned int lds_uint;
typedef __attribute__((address_space(1))) const unsigned int gbl_uint;

__device__ __forceinline__ void load16_to_lds(const void* g, void* l) {
    __builtin_amdgcn_global_load_lds((gbl_uint*)g, (lds_uint*)l, 16, 0, 0);
}

// ---------------------------------------------------------------------------
// fallback: write zeros to out (signals "workspace too small" cleanly)
__global__ __launch_bounds__(64) void zero_out_k(float* out, int n) {
    int i = blockIdx.x * 64 + threadIdx.x;
    if (i < n) out[i] = 0.0f;
}

// k0: zero counters / accumulators
__global__ __launch_bounds__(256) void init_k(int* deg_cnt, int* cursor,
                                              float* gsum, int* gcnt, int n) {
    int i = blockIdx.x * 256 + threadIdx.x;
    if (i < n) { deg_cnt[i] = 0; cursor[i] = 0; }
    if (i < NGRAPH * 512) gsum[i] = 0.0f;
    if (i < NGRAPH) gcnt[i] = 0;
}

// k1: in-degree histogram over col
__global__ __launch_bounds__(256) void deg_k(const int* __restrict__ col,
                                             int* __restrict__ deg_cnt, int e) {
    int i = blockIdx.x * 256 + threadIdx.x;
    if (i < e) atomicAdd(&deg_cnt[col[i]], 1);
}

// k2: dis = rsqrt(deg + 1)
__global__ __launch_bounds__(256) void dis_k(const int* __restrict__ deg_cnt,
                                             float* __restrict__ dis, int n) {
    int i = blockIdx.x * 256 + threadIdx.x;
    if (i < n) dis[i] = rsqrtf((float)(deg_cnt[i] + 1));
}

// k3: single-block exclusive scan
__global__ __launch_bounds__(1024) void scan_k(const int* __restrict__ cnt,
                                               int* __restrict__ offs, int n) {
    __shared__ int sbuf[1024];
    int t = threadIdx.x;
    int chunk = (n + 1023) / 1024;
    int beg = t * chunk;
    int end = min(beg + chunk, n);
    int s = 0;
    for (int i = beg; i < end; ++i) s += cnt[i];
    sbuf[t] = s;
    __syncthreads();
    for (int off = 1; off < 1024; off <<= 1) {
        int v = (t >= off) ? sbuf[t - off] : 0;
        __syncthreads();
        sbuf[t] += v;
        __syncthreads();
    }
    int run = sbuf[t] - s;
    for (int i = beg; i < end; ++i) { offs[i] = run; run += cnt[i]; }
    if (t == 1023) offs[n] = sbuf[1023];
}

// k4: scatter edges into dest-keyed CSR; weight = dis[src]
__global__ __launch_bounds__(256) void scatter_k(const int* __restrict__ row,
                                                 const int* __restrict__ col,
                                                 const int* __restrict__ offs,
                                                 int* __restrict__ cursor,
                                                 int* __restrict__ ssrc,
                                                 float* __restrict__ sw,
                                                 const float* __restrict__ dis, int e) {
    int i = blockIdx.x * 256 + threadIdx.x;
    if (i >= e) return;
    int d = col[i];
    int p = offs[d] + atomicAdd(&cursor[d], 1);
    int s = row[i];
    ssrc[p] = s;
    sw[p]   = dis[s];
}

// k5: aggregate x (F=3) fp32
__global__ __launch_bounds__(256) void agg3_k(const float* __restrict__ x,
                                              float* __restrict__ out,
                                              const int* __restrict__ offs,
                                              const int* __restrict__ ssrc,
                                              const float* __restrict__ sw,
                                              const float* __restrict__ dis, int n) {
    int d = blockIdx.x * 256 + threadIdx.x;
    if (d >= n) return;
    float dd = dis[d];
    float a0 = dd * x[d * 3 + 0];
    float a1 = dd * x[d * 3 + 1];
    float a2 = dd * x[d * 3 + 2];
    int beg = offs[d], end = offs[d + 1];
    for (int e = beg; e < end; ++e) {
        int s = ssrc[e];
        float w = sw[e];
        a0 += w * x[s * 3 + 0];
        a1 += w * x[s * 3 + 1];
        a2 += w * x[s * 3 + 2];
    }
    out[d * 3 + 0] = dd * a0;
    out[d * 3 + 1] = dd * a1;
    out[d * 3 + 2] = dd * a2;
}

// k6: h1 = relu(aggx[N,3] @ W1[3,512] + b1) -> bf16
__global__ __launch_bounds__(256) void gemm1_k(const float* __restrict__ aggx,
                                               const float* __restrict__ W1,
                                               const float* __restrict__ b1,
                                               __hip_bfloat16* __restrict__ h1) {
    int d = blockIdx.x;
    int t = threadIdx.x;
    float a0 = aggx[d * 3 + 0], a1 = aggx[d * 3 + 1], a2 = aggx[d * 3 + 2];
    for (int f = t; f < 512; f += 256) {
        float v = b1[f] + a0 * W1[f] + a1 * W1[512 + f] + a2 * W1[1024 + f];
        h1[(size_t)d * 512 + f] = __float2bfloat16(fmaxf(v, 0.0f));
    }
}

__device__ inline float bs2f(short v) {
    return __uint_as_float(((unsigned int)(unsigned short)v) << 16);
}

// k7: aggregation F=512, one WAVE per node, 16B loads, edge loop unrolled x4
__global__ __launch_bounds__(256) void agg512w_k(const __hip_bfloat16* __restrict__ in,
                                                 __hip_bfloat16* __restrict__ out,
                                                 const int* __restrict__ offs,
                                                 const int* __restrict__ ssrc,
                                                 const float* __restrict__ sw,
                                                 const float* __restrict__ dis,
                                                 const float* __restrict__ bias,
                                                 int relu, int n) {
    int wave = threadIdx.x >> 6;
    int lane = threadIdx.x & 63;
    int d = blockIdx.x * 4 + wave;
    if (d >= n) return;
    float dd = dis[d];
    short8 p = *(const short8*)&in[(size_t)d * 512 + lane * 8];
    float acc[8];
#pragma unroll
    for (int j = 0; j < 8; ++j) acc[j] = dd * bs2f(p[j]);

    int beg = offs[d], end = offs[d + 1];
    int e = beg;
    for (; e + 3 < end; e += 4) {
        int s0 = ssrc[e],     s1 = ssrc[e + 1];
        int s2 = ssrc[e + 2], s3 = ssrc[e + 3];
        float w0 = sw[e],     w1 = sw[e + 1];
        float w2 = sw[e + 2], w3 = sw[e + 3];
        short8 q0 = *(const short8*)&in[(size_t)s0 * 512 + lane * 8];
        short8 q1 = *(const short8*)&in[(size_t)s1 * 512 + lane * 8];
        short8 q2 = *(const short8*)&in[(size_t)s2 * 512 + lane * 8];
        short8 q3 = *(const short8*)&in[(size_t)s3 * 512 + lane * 8];
#pragma unroll
        for (int j = 0; j < 8; ++j) acc[j] += w0 * bs2f(q0[j]);
#pragma unroll
        for (int j = 0; j < 8; ++j) acc[j] += w1 * bs2f(q1[j]);
#pragma unroll
        for (int j = 0; j < 8; ++j) acc[j] += w2 * bs2f(q2[j]);
#pragma unroll
        for (int j = 0; j < 8; ++j) acc[j] += w3 * bs2f(q3[j]);
    }
    for (; e < end; ++e) {
        int s0 = ssrc[e];
        float w0 = sw[e];
        short8 q0 = *(const short8*)&in[(size_t)s0 * 512 + lane * 8];
#pragma unroll
        for (int j = 0; j < 8; ++j) acc[j] += w0 * bs2f(q0[j]);
    }

    short8 ov;
#pragma unroll
    for (int j = 0; j < 8; ++j) {
        float v = acc[j] * dd;
        if (bias) v += bias[lane * 8 + j];
        if (relu) v = fmaxf(v, 0.0f);
        __hip_bfloat16 h = __float2bfloat16(v);
        ov[j] = *(short*)&h;
    }
    *(short8*)&out[(size_t)d * 512 + lane * 8] = ov;
}

// k-tc: tiled transpose + f32->bf16 convert: W[K][N] -> Wt[N][K]
__global__ __launch_bounds__(256) void tcvt_k(const float* __restrict__ W,
                                              __hip_bfloat16* __restrict__ Wt,
                                              int K, int N) {
    __shared__ float tile[32][33];
    int t = threadIdx.x;
    int bn = blockIdx.x * 32;
    int bk = blockIdx.y * 32;
    int c = t & 31, r0 = t >> 5;
#pragma unroll
    for (int j = 0; j < 4; ++j) {
        int r = r0 + j * 8;
        tile[r][c] = W[(size_t)(bk + r) * N + bn + c];
    }
    __syncthreads();
#pragma unroll
    for (int j = 0; j < 4; ++j) {
        int r = r0 + j * 8;
        Wt[(size_t)(bn + r) * K + bk + c] = __float2bfloat16(tile[c][r]);
    }
}

// k8: bf16 MFMA GEMM: C[M,N] = epi(A[M,K] @ Bt[N,K]^T + bias)
// 128x128 tile, BK=32, 4 waves (2x2, each 64x64 via 4x4 16x16x32 MFMA).
// - Fragment-major global_load_lds staging (conflict-free ds_read_b128).
// - DOUBLE-BUFFERED staging (2x16KB), ONE barrier per K-iter: prefetch k+1
//   overlaps ds_read+MFMA of k (barrier still drains vmcnt; overlap is
//   within-iter + cross-block).
// - XCD-aware 1D grid swizzle: the (1<<lnbx) column-blocks sharing an A
//   row-tile all get the same blockIdx%8 -> same XCD -> A tile fetched once
//   per XCD L2 instead of 8x.
// Requires: K%32==0, N%(128<<0)==..., grid.x = nby8 * (1<<lnbx) with nby8%8==0.
__global__ __launch_bounds__(256) void mfma_gemm_k(const __hip_bfloat16* __restrict__ A,
                                                   const __hip_bfloat16* __restrict__ Bt,
                                                   const float* __restrict__ bias,
                                                   __hip_bfloat16* __restrict__ C,
                                                   int M, int N, int K, int relu,
                                                   int lnbx) {
    __shared__ short smem[17408];   // staging 2x8192 shorts / epi 128x136

    int tid  = threadIdx.x;
    int lane = tid & 63;
    int wave = tid >> 6;
    int wm = (wave >> 1) * 64;
    int wn = (wave & 1) * 64;
    int fr = lane & 15;
    int kg = lane >> 4;

    // swizzled block decode: same bm-group => same blockIdx%8 => same XCD
    int b  = blockIdx.x;
    int r8 = b & 7;
    int j  = (b >> 3) & ((1 << lnbx) - 1);
    int g8 = b >> (3 + lnbx);
    int bm = (g8 * 8 + r8) * 128;
    int bn = j * 128;

    // per-thread global source pointers for this wave's 4 staging segments
    const __hip_bfloat16* gsrc[4];
#pragma unroll
    for (int i = 0; i < 4; ++i) {
        int s = wave * 4 + i;
        if (s < 8) {
            int g = bm + s * 16 + fr;
            g = min(g, M - 1);           // edge rows clamped; never stored
            gsrc[i] = A + (size_t)g * K + kg * 8;
        } else {
            int g = bn + (s - 8) * 16 + fr;
            gsrc[i] = Bt + (size_t)g * K + kg * 8;
        }
    }

    floatx4 acc[4][4] = {};

    // prologue: stage tile 0 into buffer 0
#pragma unroll
    for (int i = 0; i < 4; ++i) {
        int s = wave * 4 + i;
        load16_to_lds(gsrc[i], &smem[s * 512]);
        gsrc[i] += 32;
    }

    int cur = 0;
    for (int k0 = 0; k0 < K; k0 += 32) {
        __syncthreads();   // tile[cur] loads complete; prev ds_reads done
        int nxt = cur ^ 8192;
        if (k0 + 32 < K) {
#pragma unroll
            for (int i = 0; i < 4; ++i) {
                int s = wave * 4 + i;
                load16_to_lds(gsrc[i], &smem[nxt + s * 512]);
                gsrc[i] += 32;
            }
        }

        short8 af[4], bf[4];
#pragma unroll
        for (int mi = 0; mi < 4; ++mi)
            af[mi] = *(short8*)&smem[cur + ((wm >> 4) + mi) * 512 + lane * 8];
#pragma unroll
        for (int ni = 0; ni < 4; ++ni)
            bf[ni] = *(short8*)&smem[cur + (8 + (wn >> 4) + ni) * 512 + lane * 8];
#pragma unroll
        for (int mi = 0; mi < 4; ++mi)
#pragma unroll
            for (int ni = 0; ni < 4; ++ni)
                acc[mi][ni] = __builtin_amdgcn_mfma_f32_16x16x32_bf16(
                    af[mi], bf[ni], acc[mi][ni], 0, 0, 0);
        cur = nxt;
    }
    __syncthreads();   // all ds_reads done before smem reuse as Cs

    // epilogue: bias+relu, repack via LDS, coalesced 16B stores
    short* Cs = smem;   // [128][136]
#pragma unroll
    for (int mi = 0; mi < 4; ++mi) {
#pragma unroll
        for (int ni = 0; ni < 4; ++ni) {
            int rl = wm + mi * 16 + (lane >> 4) * 4;
            int cl = wn + ni * 16 + (lane & 15);
            float bv = bias ? bias[bn + cl] : 0.0f;
#pragma unroll
            for (int r = 0; r < 4; ++r) {
                float v = acc[mi][ni][r] + bv;
                if (relu) v = fmaxf(v, 0.0f);
                __hip_bfloat16 h = __float2bfloat16(v);
                Cs[(rl + r) * 136 + cl] = *(short*)&h;
            }
        }
    }
    __syncthreads();
#pragma unroll
    for (int i = 0; i < 8; ++i) {
        int c  = tid + 256 * i;
        int rr = c >> 4;
        int cc = c & 15;
        int grow = bm + rr;
        if (grow < M)
            *(short8*)&C[(size_t)grow * N + bn + cc * 8] =
                *(short8*)&Cs[rr * 136 + cc * 8];
    }
}

// k9: per-graph node counts — LDS histogram
__global__ __launch_bounds__(256) void count_k(const int* __restrict__ batch,
                                               int* __restrict__ gcnt, int n) {
    __shared__ int h[NGRAPH];
    int t = threadIdx.x;
    if (t < NGRAPH) h[t] = 0;
    __syncthreads();
    for (int i = blockIdx.x * 256 + t; i < n; i += gridDim.x * 256)
        atomicAdd(&h[batch[i]], 1);
    __syncthreads();
    if (t < NGRAPH) atomicAdd(&gcnt[t], h[t]);
}

// k10: pooled sums, bf16 input, LDS fp32 accumulators
__global__ __launch_bounds__(256) void pool_k(const __hip_bfloat16* __restrict__ h,
                                              const int* __restrict__ batch,
                                              float* __restrict__ gsum, int n) {
    __shared__ float ls[NGRAPH * 512];
    int t = threadIdx.x;
    for (int i = t; i < NGRAPH * 512; i += 256) ls[i] = 0.0f;
    __syncthreads();
    for (int d = blockIdx.x; d < n; d += gridDim.x) {
        int g = batch[d];
        unsigned int q = *(const unsigned int*)&h[(size_t)d * 512 + 2 * t];
        ls[g * 512 + 2 * t]     += __uint_as_float((q & 0xffffu) << 16);
        ls[g * 512 + 2 * t + 1] += __uint_as_float((q >> 16) << 16);
    }
    __syncthreads();
    for (int i = t; i < NGRAPH * 512; i += 256) atomicAdd(&gsum[i], ls[i]);
}

// k11: head MLP (fp32)
__global__ __launch_bounds__(128) void fc_k(const float* __restrict__ gsum,
                                            const int* __restrict__ gcnt,
                                            const float* __restrict__ fcw1,
                                            const float* __restrict__ fcb1,
                                            const float* __restrict__ fcw2,
                                            const float* __restrict__ fcb2,
                                            float* __restrict__ out) {
    int g = blockIdx.x;
    int t = threadIdx.x;  // 128
    __shared__ float pooled[512];
    __shared__ float red[128];
    float inv = 1.0f / fmaxf((float)gcnt[g], 1.0f);
    for (int i = t; i < 512; i += 128) pooled[i] = gsum[g * 512 + i] * inv;
    __syncthreads();
    float s = fcb1[t];
    for (int k = 0; k < 512; ++k) s += pooled[k] * fcw1[k * 128 + t];
    s = fmaxf(s, 0.0f);
    red[t] = s * fcw2[t];
    __syncthreads();
    for (int off = 64; off > 0; off >>= 1) {
        if (t < off) red[t] += red[t + off];
        __syncthreads();
    }
    if (t == 0) out[g] = red[0] + fcb2[0];
}

extern "C" void kernel_launch(void* const* d_in, const int* in_sizes, int n_in,
                              void* d_out, int out_size, void* d_ws, size_t ws_size,
                              hipStream_t stream) {
    const float* x    = (const float*)d_in[0];
    const int*   ei   = (const int*)d_in[1];   // [2, E]
    const int*   batch= (const int*)d_in[2];
    const float* W1   = (const float*)d_in[3];
    const float* b1   = (const float*)d_in[4];
    const float* W2   = (const float*)d_in[5];
    const float* b2   = (const float*)d_in[6];
    const float* W3   = (const float*)d_in[7];
    const float* b3   = (const float*)d_in[8];
    const float* fcw1 = (const float*)d_in[9];
    const float* fcb1 = (const float*)d_in[10];
    const float* fcw2 = (const float*)d_in[11];
    const float* fcb2 = (const float*)d_in[12];
    float* out = (float*)d_out;

    const int N = in_sizes[0] / 3;      // 50000
    const int E = in_sizes[1] / 2;      // 400000
    const int* row = ei;
    const int* col = ei + E;

    // ---- workspace layout ----
    size_t used = 0;
    auto need = [&](size_t bytes) {
        size_t off = used;
        used += (bytes + 255) & ~(size_t)255;
        return off;
    };
    size_t o_deg  = need((size_t)N * 4);
    size_t o_cur  = need((size_t)N * 4);
    size_t o_dis  = need((size_t)N * 4);
    size_t o_offs = need((size_t)(N + 1) * 4);
    size_t o_ssrc = need((size_t)E * 4);
    size_t o_sw   = need((size_t)E * 4);
    size_t o_aggx = need((size_t)N * 3 * 4);
    size_t o_gsum = need((size_t)NGRAPH * 512 * 4);
    size_t o_gcnt = need((size_t)NGRAPH * 4);
    size_t o_w2t  = need((size_t)512 * 1024 * 2);   // W2^T bf16 [1024][512]
    size_t o_w3t  = need((size_t)1024 * 512 * 2);   // W3^T bf16 [512][1024]
    size_t o_bufX = need((size_t)N * 512 * 2);      // h1 -> g3   (bf16)
    size_t o_bufY = need((size_t)N * 512 * 2);      // agg1 -> h3 (bf16)
    size_t o_bufZ = need((size_t)N * 1024 * 2);     // h2         (bf16)

    if (used > ws_size) {
        hipLaunchKernelGGL(zero_out_k, dim3((out_size + 63) / 64), dim3(64), 0, stream,
                           out, out_size);
        return;
    }

    char* base = (char*)d_ws;
    int*   deg_cnt = (int*)  (base + o_deg);
    int*   cursor  = (int*)  (base + o_cur);
    float* dis     = (float*)(base + o_dis);
    int*   offs    = (int*)  (base + o_offs);
    int*   ssrc    = (int*)  (base + o_ssrc);
    float* sw      = (float*)(base + o_sw);
    float* aggx    = (float*)(base + o_aggx);
    float* gsum    = (float*)(base + o_gsum);
    int*   gcnt    = (int*)  (base + o_gcnt);
    __hip_bfloat16* w2t  = (__hip_bfloat16*)(base + o_w2t);
    __hip_bfloat16* w3t  = (__hip_bfloat16*)(base + o_w3t);
    __hip_bfloat16* bufX = (__hip_bfloat16*)(base + o_bufX);
    __hip_bfloat16* bufY = (__hip_bfloat16*)(base + o_bufY);
    __hip_bfloat16* bufZ = (__hip_bfloat16*)(base + o_bufZ);
    (void)n_in;

    int gN = (N + 255) / 256;
    int gE = (E + 255) / 256;
    int gW = (N + 3) / 4;            // wave-per-node grids
    int nby8 = (((N + 127) / 128 + 7) / 8) * 8;   // row tiles, padded to x8

    // CSR build + norm
    hipLaunchKernelGGL(init_k, dim3(gN), dim3(256), 0, stream, deg_cnt, cursor, gsum, gcnt, N);
    hipLaunchKernelGGL(deg_k, dim3(gE), dim3(256), 0, stream, col, deg_cnt, E);
    hipLaunchKernelGGL(dis_k, dim3(gN), dim3(256), 0, stream, deg_cnt, dis, N);
    hipLaunchKernelGGL(scan_k, dim3(1), dim3(1024), 0, stream, deg_cnt, offs, N);
    hipLaunchKernelGGL(scatter_k, dim3(gE), dim3(256), 0, stream, row, col, offs, cursor, ssrc, sw, dis, E);

    // weights: transpose + bf16 convert
    hipLaunchKernelGGL(tcvt_k, dim3(1024 / 32, 512 / 32), dim3(256), 0, stream, W2, w2t, 512, 1024);
    hipLaunchKernelGGL(tcvt_k, dim3(512 / 32, 1024 / 32), dim3(256), 0, stream, W3, w3t, 1024, 512);

    // layer 1: agg(F=3) fp32, then 3->512 GEMM -> h1 bf16
    hipLaunchKernelGGL(agg3_k, dim3(gN), dim3(256), 0, stream, x, aggx, offs, ssrc, sw, dis, N);
    hipLaunchKernelGGL(gemm1_k, dim3(N), dim3(256), 0, stream, aggx, W1, b1, bufX);

    // layer 2: agg1 = A_norm h1, h2 = relu(agg1 @ W2 + b2)
    hipLaunchKernelGGL(agg512w_k, dim3(gW), dim3(256), 0, stream, bufX, bufY, offs, ssrc, sw, dis,
                       (const float*)nullptr, 0, N);
    hipLaunchKernelGGL(mfma_gemm_k, dim3(nby8 * 8), dim3(256), 0, stream,
                       bufY, w2t, b2, bufZ, N, 1024, 512, 1, 3);

    // layer 3: g3 = h2 @ W3, h3 = relu(A_norm g3 + b3)
    hipLaunchKernelGGL(mfma_gemm_k, dim3(nby8 * 4), dim3(256), 0, stream,
                       bufZ, w3t, (const float*)nullptr, bufX, N, 512, 1024, 0, 2);
    hipLaunchKernelGGL(agg512w_k, dim3(gW), dim3(256), 0, stream, bufX, bufY, offs, ssrc, sw, dis,
                       b3, 1, N);

    // mean pool + head
    hipLaunchKernelGGL(count_k, dim3(64), dim3(256), 0, stream, batch, gcnt, N);
    hipLaunchKernelGGL(pool_k, dim3(256), dim3(256), 0, stream, bufY, batch, gsum, N);
    hipLaunchKernelGGL(fc_k, dim3(NGRAPH), dim3(128), 0, stream, gsum, gcnt, fcw1, fcb1, fcw2, fcb2, out);
}

// Round 7
// 696.715 us; speedup vs baseline: 4.1335x; 1.0061x over previous
//
#include <hip/hip_runtime.h>
#include <hip/hip_bf16.h>

#define NNODES 50000
#define NEDGES 400000
#define NGRAPH 16

typedef __attribute__((ext_vector_type(4))) float floatx4;
typedef __attribute__((ext_vector_type(8))) short short8;

typedef __attribute__((address_space(3))) unsigned int lds_uint;
typedef __attribute__((address_space(1))) const unsigned int gbl_uint;

__device__ __forceinline__ void load16_to_lds(const void* g, void* l) {
    __builtin_amdgcn_global_load_lds((gbl_uint*)g, (lds_uint*)l, 16, 0, 0);
}

// ---------------------------------------------------------------------------
__global__ __launch_bounds__(64) void zero_out_k(float* out, int n) {
    int i = blockIdx.x * 64 + threadIdx.x;
    if (i < n) out[i] = 0.0f;
}

__global__ __launch_bounds__(256) void init_k(int* deg_cnt, int* cursor,
                                              float* gsum, int* gcnt, int n) {
    int i = blockIdx.x * 256 + threadIdx.x;
    if (i < n) { deg_cnt[i] = 0; cursor[i] = 0; }
    if (i < NGRAPH * 512) gsum[i] = 0.0f;
    if (i < NGRAPH) gcnt[i] = 0;
}

__global__ __launch_bounds__(256) void deg_k(const int* __restrict__ col,
                                             int* __restrict__ deg_cnt, int e) {
    int i = blockIdx.x * 256 + threadIdx.x;
    if (i < e) atomicAdd(&deg_cnt[col[i]], 1);
}

__global__ __launch_bounds__(256) void dis_k(const int* __restrict__ deg_cnt,
                                             float* __restrict__ dis, int n) {
    int i = blockIdx.x * 256 + threadIdx.x;
    if (i < n) dis[i] = rsqrtf((float)(deg_cnt[i] + 1));
}

__global__ __launch_bounds__(1024) void scan_k(const int* __restrict__ cnt,
                                               int* __restrict__ offs, int n) {
    __shared__ int sbuf[1024];
    int t = threadIdx.x;
    int chunk = (n + 1023) / 1024;
    int beg = t * chunk;
    int end = min(beg + chunk, n);
    int s = 0;
    for (int i = beg; i < end; ++i) s += cnt[i];
    sbuf[t] = s;
    __syncthreads();
    for (int off = 1; off < 1024; off <<= 1) {
        int v = (t >= off) ? sbuf[t - off] : 0;
        __syncthreads();
        sbuf[t] += v;
        __syncthreads();
    }
    int run = sbuf[t] - s;
    for (int i = beg; i < end; ++i) { offs[i] = run; run += cnt[i]; }
    if (t == 1023) offs[n] = sbuf[1023];
}

__global__ __launch_bounds__(256) void scatter_k(const int* __restrict__ row,
                                                 const int* __restrict__ col,
                                                 const int* __restrict__ offs,
                                                 int* __restrict__ cursor,
                                                 int* __restrict__ ssrc,
                                                 float* __restrict__ sw,
                                                 const float* __restrict__ dis, int e) {
    int i = blockIdx.x * 256 + threadIdx.x;
    if (i >= e) return;
    int d = col[i];
    int p = offs[d] + atomicAdd(&cursor[d], 1);
    int s = row[i];
    ssrc[p] = s;
    sw[p]   = dis[s];
}

__global__ __launch_bounds__(256) void agg3_k(const float* __restrict__ x,
                                              float* __restrict__ out,
                                              const int* __restrict__ offs,
                                              const int* __restrict__ ssrc,
                                              const float* __restrict__ sw,
                                              const float* __restrict__ dis, int n) {
    int d = blockIdx.x * 256 + threadIdx.x;
    if (d >= n) return;
    float dd = dis[d];
    float a0 = dd * x[d * 3 + 0];
    float a1 = dd * x[d * 3 + 1];
    float a2 = dd * x[d * 3 + 2];
    int beg = offs[d], end = offs[d + 1];
    for (int e = beg; e < end; ++e) {
        int s = ssrc[e];
        float w = sw[e];
        a0 += w * x[s * 3 + 0];
        a1 += w * x[s * 3 + 1];
        a2 += w * x[s * 3 + 2];
    }
    out[d * 3 + 0] = dd * a0;
    out[d * 3 + 1] = dd * a1;
    out[d * 3 + 2] = dd * a2;
}

__global__ __launch_bounds__(256) void gemm1_k(const float* __restrict__ aggx,
                                               const float* __restrict__ W1,
                                               const float* __restrict__ b1,
                                               __hip_bfloat16* __restrict__ h1) {
    int d = blockIdx.x;
    int t = threadIdx.x;
    float a0 = aggx[d * 3 + 0], a1 = aggx[d * 3 + 1], a2 = aggx[d * 3 + 2];
    for (int f = t; f < 512; f += 256) {
        float v = b1[f] + a0 * W1[f] + a1 * W1[512 + f] + a2 * W1[1024 + f];
        h1[(size_t)d * 512 + f] = __float2bfloat16(fmaxf(v, 0.0f));
    }
}

__device__ inline float bs2f(short v) {
    return __uint_as_float(((unsigned int)(unsigned short)v) << 16);
}

// aggregation F=512, one WAVE per node, 16B loads, edge loop unrolled x4
__global__ __launch_bounds__(256) void agg512w_k(const __hip_bfloat16* __restrict__ in,
                                                 __hip_bfloat16* __restrict__ out,
                                                 const int* __restrict__ offs,
                                                 const int* __restrict__ ssrc,
                                                 const float* __restrict__ sw,
                                                 const float* __restrict__ dis,
                                                 const float* __restrict__ bias,
                                                 int relu, int n) {
    int wave = threadIdx.x >> 6;
    int lane = threadIdx.x & 63;
    int d = blockIdx.x * 4 + wave;
    if (d >= n) return;
    float dd = dis[d];
    short8 p = *(const short8*)&in[(size_t)d * 512 + lane * 8];
    float acc[8];
#pragma unroll
    for (int j = 0; j < 8; ++j) acc[j] = dd * bs2f(p[j]);

    int beg = offs[d], end = offs[d + 1];
    int e = beg;
    for (; e + 3 < end; e += 4) {
        int s0 = ssrc[e],     s1 = ssrc[e + 1];
        int s2 = ssrc[e + 2], s3 = ssrc[e + 3];
        float w0 = sw[e],     w1 = sw[e + 1];
        float w2 = sw[e + 2], w3 = sw[e + 3];
        short8 q0 = *(const short8*)&in[(size_t)s0 * 512 + lane * 8];
        short8 q1 = *(const short8*)&in[(size_t)s1 * 512 + lane * 8];
        short8 q2 = *(const short8*)&in[(size_t)s2 * 512 + lane * 8];
        short8 q3 = *(const short8*)&in[(size_t)s3 * 512 + lane * 8];
#pragma unroll
        for (int j = 0; j < 8; ++j) acc[j] += w0 * bs2f(q0[j]);
#pragma unroll
        for (int j = 0; j < 8; ++j) acc[j] += w1 * bs2f(q1[j]);
#pragma unroll
        for (int j = 0; j < 8; ++j) acc[j] += w2 * bs2f(q2[j]);
#pragma unroll
        for (int j = 0; j < 8; ++j) acc[j] += w3 * bs2f(q3[j]);
    }
    for (; e < end; ++e) {
        int s0 = ssrc[e];
        float w0 = sw[e];
        short8 q0 = *(const short8*)&in[(size_t)s0 * 512 + lane * 8];
#pragma unroll
        for (int j = 0; j < 8; ++j) acc[j] += w0 * bs2f(q0[j]);
    }

    short8 ov;
#pragma unroll
    for (int j = 0; j < 8; ++j) {
        float v = acc[j] * dd;
        if (bias) v += bias[lane * 8 + j];
        if (relu) v = fmaxf(v, 0.0f);
        __hip_bfloat16 h = __float2bfloat16(v);
        ov[j] = *(short*)&h;
    }
    *(short8*)&out[(size_t)d * 512 + lane * 8] = ov;
}

// tiled transpose + f32->bf16 convert: W[K][N] -> Wt[N][K]
__global__ __launch_bounds__(256) void tcvt_k(const float* __restrict__ W,
                                              __hip_bfloat16* __restrict__ Wt,
                                              int K, int N) {
    __shared__ float tile[32][33];
    int t = threadIdx.x;
    int bn = blockIdx.x * 32;
    int bk = blockIdx.y * 32;
    int c = t & 31, r0 = t >> 5;
#pragma unroll
    for (int j = 0; j < 4; ++j) {
        int r = r0 + j * 8;
        tile[r][c] = W[(size_t)(bk + r) * N + bn + c];
    }
    __syncthreads();
#pragma unroll
    for (int j = 0; j < 4; ++j) {
        int r = r0 + j * 8;
        Wt[(size_t)(bn + r) * K + bk + c] = __float2bfloat16(tile[c][r]);
    }
}

// bf16 MFMA GEMM: C[M,N] = epi(A[M,K] @ Bt[N,K]^T + bias)
// 256x128 block tile, BK=32, 4 waves (2x2; wave tile 128x64 = 8x4 16x16x32).
// - Fragment-major global_load_lds staging, double-buffered (2x24KB),
//   one barrier per K-iter. 24 segments/tile: 0..15 = A rows, 16..23 = B rows.
// - XCD swizzle: (1<<lnbx) col-blocks sharing an A row-tile get same
//   blockIdx%8 -> same XCD L2.
// - Epilogue: two 128-row passes through a 128x136 LDS window (stays in the
//   48KB staging region; keeps LDS/block under 64KB).
// __launch_bounds__(256,2): cap VGPRs ~256 -> 2 blocks/CU.
__global__ __launch_bounds__(256, 2) void mfma_gemm_k(const __hip_bfloat16* __restrict__ A,
                                                      const __hip_bfloat16* __restrict__ Bt,
                                                      const float* __restrict__ bias,
                                                      __hip_bfloat16* __restrict__ C,
                                                      int M, int N, int K, int relu,
                                                      int lnbx) {
    __shared__ short smem[24576];   // 48KB: 2 x (24 segs x 512 shorts)

    int tid  = threadIdx.x;
    int lane = tid & 63;
    int wave = tid >> 6;
    int wm = (wave >> 1) * 128;     // 0 or 128
    int wn = (wave & 1) * 64;       // 0 or 64
    int fr = lane & 15;
    int kg = lane >> 4;

    // swizzled block decode
    int b  = blockIdx.x;
    int r8 = b & 7;
    int j  = (b >> 3) & ((1 << lnbx) - 1);
    int g8 = b >> (3 + lnbx);
    int bm = (g8 * 8 + r8) * 256;
    int bn = j * 128;

    // 24 staging segments, 6 per wave
    const __hip_bfloat16* gsrc[6];
#pragma unroll
    for (int i = 0; i < 6; ++i) {
        int s = wave * 6 + i;
        if (s < 16) {
            int g = bm + s * 16 + fr;
            g = min(g, M - 1);          // edge rows clamped; never stored
            gsrc[i] = A + (size_t)g * K + kg * 8;
        } else {
            int g = bn + (s - 16) * 16 + fr;
            gsrc[i] = Bt + (size_t)g * K + kg * 8;
        }
    }

    floatx4 acc[8][4] = {};

    // prologue: stage tile 0 into buffer 0
#pragma unroll
    for (int i = 0; i < 6; ++i) {
        load16_to_lds(gsrc[i], &smem[(wave * 6 + i) * 512]);
        gsrc[i] += 32;
    }

    int cur = 0;
    for (int k0 = 0; k0 < K; k0 += 32) {
        __syncthreads();   // tile[cur] staged; prev ds_reads done
        int nxt = cur ^ 12288;
        if (k0 + 32 < K) {
#pragma unroll
            for (int i = 0; i < 6; ++i) {
                load16_to_lds(gsrc[i], &smem[nxt + (wave * 6 + i) * 512]);
                gsrc[i] += 32;
            }
        }

        short8 bf[4], af[8];
#pragma unroll
        for (int ni = 0; ni < 4; ++ni)
            bf[ni] = *(short8*)&smem[cur + (16 + (wn >> 4) + ni) * 512 + lane * 8];
#pragma unroll
        for (int mi = 0; mi < 8; ++mi)
            af[mi] = *(short8*)&smem[cur + ((wm >> 4) + mi) * 512 + lane * 8];
#pragma unroll
        for (int mi = 0; mi < 8; ++mi)
#pragma unroll
            for (int ni = 0; ni < 4; ++ni)
                acc[mi][ni] = __builtin_amdgcn_mfma_f32_16x16x32_bf16(
                    af[mi], bf[ni], acc[mi][ni], 0, 0, 0);
        cur = nxt;
    }

    // epilogue: two 128-row passes through Cs[128][136] (reuses staging LDS)
    short* Cs = smem;
#pragma unroll
    for (int half = 0; half < 2; ++half) {
        __syncthreads();   // staging reads / previous pass stores done
        if ((wave >> 1) == half) {
#pragma unroll
            for (int mi = 0; mi < 8; ++mi) {
#pragma unroll
                for (int ni = 0; ni < 4; ++ni) {
                    int rl = mi * 16 + (lane >> 4) * 4;   // row in window
                    int cl = wn + ni * 16 + (lane & 15);
                    float bv = bias ? bias[bn + cl] : 0.0f;
#pragma unroll
                    for (int r = 0; r < 4; ++r) {
                        float v = acc[mi][ni][r] + bv;
                        if (relu) v = fmaxf(v, 0.0f);
                        __hip_bfloat16 h = __float2bfloat16(v);
                        Cs[(rl + r) * 136 + cl] = *(short*)&h;
                    }
                }
            }
        }
        __syncthreads();
#pragma unroll
        for (int i = 0; i < 8; ++i) {
            int c  = tid + 256 * i;     // 0..2047
            int rr = c >> 4;            // 0..127 (window row)
            int cc = c & 15;
            int grow = bm + half * 128 + rr;
            if (grow < M)
                *(short8*)&C[(size_t)grow * N + bn + cc * 8] =
                    *(short8*)&Cs[rr * 136 + cc * 8];
        }
    }
}

// per-graph node counts — LDS histogram
__global__ __launch_bounds__(256) void count_k(const int* __restrict__ batch,
                                               int* __restrict__ gcnt, int n) {
    __shared__ int h[NGRAPH];
    int t = threadIdx.x;
    if (t < NGRAPH) h[t] = 0;
    __syncthreads();
    for (int i = blockIdx.x * 256 + t; i < n; i += gridDim.x * 256)
        atomicAdd(&h[batch[i]], 1);
    __syncthreads();
    if (t < NGRAPH) atomicAdd(&gcnt[t], h[t]);
}

// pooled sums, bf16 input, LDS fp32 accumulators
__global__ __launch_bounds__(256) void pool_k(const __hip_bfloat16* __restrict__ h,
                                              const int* __restrict__ batch,
                                              float* __restrict__ gsum, int n) {
    __shared__ float ls[NGRAPH * 512];
    int t = threadIdx.x;
    for (int i = t; i < NGRAPH * 512; i += 256) ls[i] = 0.0f;
    __syncthreads();
    for (int d = blockIdx.x; d < n; d += gridDim.x) {
        int g = batch[d];
        unsigned int q = *(const unsigned int*)&h[(size_t)d * 512 + 2 * t];
        ls[g * 512 + 2 * t]     += __uint_as_float((q & 0xffffu) << 16);
        ls[g * 512 + 2 * t + 1] += __uint_as_float((q >> 16) << 16);
    }
    __syncthreads();
    for (int i = t; i < NGRAPH * 512; i += 256) atomicAdd(&gsum[i], ls[i]);
}

// head MLP (fp32)
__global__ __launch_bounds__(128) void fc_k(const float* __restrict__ gsum,
                                            const int* __restrict__ gcnt,
                                            const float* __restrict__ fcw1,
                                            const float* __restrict__ fcb1,
                                            const float* __restrict__ fcw2,
                                            const float* __restrict__ fcb2,
                                            float* __restrict__ out) {
    int g = blockIdx.x;
    int t = threadIdx.x;  // 128
    __shared__ float pooled[512];
    __shared__ float red[128];
    float inv = 1.0f / fmaxf((float)gcnt[g], 1.0f);
    for (int i = t; i < 512; i += 128) pooled[i] = gsum[g * 512 + i] * inv;
    __syncthreads();
    float s = fcb1[t];
    for (int k = 0; k < 512; ++k) s += pooled[k] * fcw1[k * 128 + t];
    s = fmaxf(s, 0.0f);
    red[t] = s * fcw2[t];
    __syncthreads();
    for (int off = 64; off > 0; off >>= 1) {
        if (t < off) red[t] += red[t + off];
        __syncthreads();
    }
    if (t == 0) out[g] = red[0] + fcb2[0];
}

extern "C" void kernel_launch(void* const* d_in, const int* in_sizes, int n_in,
                              void* d_out, int out_size, void* d_ws, size_t ws_size,
                              hipStream_t stream) {
    const float* x    = (const float*)d_in[0];
    const int*   ei   = (const int*)d_in[1];   // [2, E]
    const int*   batch= (const int*)d_in[2];
    const float* W1   = (const float*)d_in[3];
    const float* b1   = (const float*)d_in[4];
    const float* W2   = (const float*)d_in[5];
    const float* b2   = (const float*)d_in[6];
    const float* W3   = (const float*)d_in[7];
    const float* b3   = (const float*)d_in[8];
    const float* fcw1 = (const float*)d_in[9];
    const float* fcb1 = (const float*)d_in[10];
    const float* fcw2 = (const float*)d_in[11];
    const float* fcb2 = (const float*)d_in[12];
    float* out = (float*)d_out;

    const int N = in_sizes[0] / 3;      // 50000
    const int E = in_sizes[1] / 2;      // 400000
    const int* row = ei;
    const int* col = ei + E;

    // ---- workspace layout ----
    size_t used = 0;
    auto need = [&](size_t bytes) {
        size_t off = used;
        used += (bytes + 255) & ~(size_t)255;
        return off;
    };
    size_t o_deg  = need((size_t)N * 4);
    size_t o_cur  = need((size_t)N * 4);
    size_t o_dis  = need((size_t)N * 4);
    size_t o_offs = need((size_t)(N + 1) * 4);
    size_t o_ssrc = need((size_t)E * 4);
    size_t o_sw   = need((size_t)E * 4);
    size_t o_aggx = need((size_t)N * 3 * 4);
    size_t o_gsum = need((size_t)NGRAPH * 512 * 4);
    size_t o_gcnt = need((size_t)NGRAPH * 4);
    size_t o_w2t  = need((size_t)512 * 1024 * 2);   // W2^T bf16 [1024][512]
    size_t o_w3t  = need((size_t)1024 * 512 * 2);   // W3^T bf16 [512][1024]
    size_t o_bufX = need((size_t)N * 512 * 2);      // h1 -> g3   (bf16)
    size_t o_bufY = need((size_t)N * 512 * 2);      // agg1 -> h3 (bf16)
    size_t o_bufZ = need((size_t)N * 1024 * 2);     // h2         (bf16)

    if (used > ws_size) {
        hipLaunchKernelGGL(zero_out_k, dim3((out_size + 63) / 64), dim3(64), 0, stream,
                           out, out_size);
        return;
    }

    char* base = (char*)d_ws;
    int*   deg_cnt = (int*)  (base + o_deg);
    int*   cursor  = (int*)  (base + o_cur);
    float* dis     = (float*)(base + o_dis);
    int*   offs    = (int*)  (base + o_offs);
    int*   ssrc    = (int*)  (base + o_ssrc);
    float* sw      = (float*)(base + o_sw);
    float* aggx    = (float*)(base + o_aggx);
    float* gsum    = (float*)(base + o_gsum);
    int*   gcnt    = (int*)  (base + o_gcnt);
    __hip_bfloat16* w2t  = (__hip_bfloat16*)(base + o_w2t);
    __hip_bfloat16* w3t  = (__hip_bfloat16*)(base + o_w3t);
    __hip_bfloat16* bufX = (__hip_bfloat16*)(base + o_bufX);
    __hip_bfloat16* bufY = (__hip_bfloat16*)(base + o_bufY);
    __hip_bfloat16* bufZ = (__hip_bfloat16*)(base + o_bufZ);
    (void)n_in;

    int gN = (N + 255) / 256;
    int gE = (E + 255) / 256;
    int gW = (N + 3) / 4;                         // wave-per-node grids
    int nby8 = (((N + 255) / 256 + 7) / 8) * 8;   // 256-row tiles, padded to x8

    // CSR build + norm
    hipLaunchKernelGGL(init_k, dim3(gN), dim3(256), 0, stream, deg_cnt, cursor, gsum, gcnt, N);
    hipLaunchKernelGGL(deg_k, dim3(gE), dim3(256), 0, stream, col, deg_cnt, E);
    hipLaunchKernelGGL(dis_k, dim3(gN), dim3(256), 0, stream, deg_cnt, dis, N);
    hipLaunchKernelGGL(scan_k, dim3(1), dim3(1024), 0, stream, deg_cnt, offs, N);
    hipLaunchKernelGGL(scatter_k, dim3(gE), dim3(256), 0, stream, row, col, offs, cursor, ssrc, sw, dis, E);

    // weights: transpose + bf16 convert
    hipLaunchKernelGGL(tcvt_k, dim3(1024 / 32, 512 / 32), dim3(256), 0, stream, W2, w2t, 512, 1024);
    hipLaunchKernelGGL(tcvt_k, dim3(512 / 32, 1024 / 32), dim3(256), 0, stream, W3, w3t, 1024, 512);

    // layer 1: agg(F=3) fp32, then 3->512 GEMM -> h1 bf16
    hipLaunchKernelGGL(agg3_k, dim3(gN), dim3(256), 0, stream, x, aggx, offs, ssrc, sw, dis, N);
    hipLaunchKernelGGL(gemm1_k, dim3(N), dim3(256), 0, stream, aggx, W1, b1, bufX);

    // layer 2: agg1 = A_norm h1, h2 = relu(agg1 @ W2 + b2)
    hipLaunchKernelGGL(agg512w_k, dim3(gW), dim3(256), 0, stream, bufX, bufY, offs, ssrc, sw, dis,
                       (const float*)nullptr, 0, N);
    hipLaunchKernelGGL(mfma_gemm_k, dim3(nby8 * 8), dim3(256), 0, stream,
                       bufY, w2t, b2, bufZ, N, 1024, 512, 1, 3);

    // layer 3: g3 = h2 @ W3, h3 = relu(A_norm g3 + b3)
    hipLaunchKernelGGL(mfma_gemm_k, dim3(nby8 * 4), dim3(256), 0, stream,
                       bufZ, w3t, (const float*)nullptr, bufX, N, 512, 1024, 0, 2);
    hipLaunchKernelGGL(agg512w_k, dim3(gW), dim3(256), 0, stream, bufX, bufY, offs, ssrc, sw, dis,
                       b3, 1, N);

    // mean pool + head
    hipLaunchKernelGGL(count_k, dim3(64), dim3(256), 0, stream, batch, gcnt, N);
    hipLaunchKernelGGL(pool_k, dim3(256), dim3(256), 0, stream, bufY, batch, gsum, N);
    hipLaunchKernelGGL(fc_k, dim3(NGRAPH), dim3(128), 0, stream, gsum, gcnt, fcw1, fcb1, fcw2, fcb2, out);
}

// Round 8
// 688.866 us; speedup vs baseline: 4.1806x; 1.0114x over previous
//
#include <hip/hip_runtime.h>
#include <hip/hip_bf16.h>

#define NNODES 50000
#define NEDGES 400000
#define NGRAPH 16

typedef __attribute__((ext_vector_type(4))) float floatx4;
typedef __attribute__((ext_vector_type(8))) short short8;

typedef __attribute__((address_space(3))) unsigned int lds_uint;
typedef __attribute__((address_space(1))) const unsigned int gbl_uint;

__device__ __forceinline__ void load16_to_lds(const void* g, void* l) {
    __builtin_amdgcn_global_load_lds((gbl_uint*)g, (lds_uint*)l, 16, 0, 0);
}

// ---------------------------------------------------------------------------
__global__ __launch_bounds__(64) void zero_out_k(float* out, int n) {
    int i = blockIdx.x * 64 + threadIdx.x;
    if (i < n) out[i] = 0.0f;
}

__global__ __launch_bounds__(256) void init_k(int* deg_cnt, int* cursor,
                                              float* gsum, int* gcnt, int n) {
    int i = blockIdx.x * 256 + threadIdx.x;
    if (i < n) { deg_cnt[i] = 0; cursor[i] = 0; }
    if (i < NGRAPH * 512) gsum[i] = 0.0f;
    if (i < NGRAPH) gcnt[i] = 0;
}

__global__ __launch_bounds__(256) void deg_k(const int* __restrict__ col,
                                             int* __restrict__ deg_cnt, int e) {
    int i = blockIdx.x * 256 + threadIdx.x;
    if (i < e) atomicAdd(&deg_cnt[col[i]], 1);
}

__global__ __launch_bounds__(256) void dis_k(const int* __restrict__ deg_cnt,
                                             float* __restrict__ dis, int n) {
    int i = blockIdx.x * 256 + threadIdx.x;
    if (i < n) dis[i] = rsqrtf((float)(deg_cnt[i] + 1));
}

__global__ __launch_bounds__(1024) void scan_k(const int* __restrict__ cnt,
                                               int* __restrict__ offs, int n) {
    __shared__ int sbuf[1024];
    int t = threadIdx.x;
    int chunk = (n + 1023) / 1024;
    int beg = t * chunk;
    int end = min(beg + chunk, n);
    int s = 0;
    for (int i = beg; i < end; ++i) s += cnt[i];
    sbuf[t] = s;
    __syncthreads();
    for (int off = 1; off < 1024; off <<= 1) {
        int v = (t >= off) ? sbuf[t - off] : 0;
        __syncthreads();
        sbuf[t] += v;
        __syncthreads();
    }
    int run = sbuf[t] - s;
    for (int i = beg; i < end; ++i) { offs[i] = run; run += cnt[i]; }
    if (t == 1023) offs[n] = sbuf[1023];
}

__global__ __launch_bounds__(256) void scatter_k(const int* __restrict__ row,
                                                 const int* __restrict__ col,
                                                 const int* __restrict__ offs,
                                                 int* __restrict__ cursor,
                                                 int* __restrict__ ssrc,
                                                 float* __restrict__ sw,
                                                 const float* __restrict__ dis, int e) {
    int i = blockIdx.x * 256 + threadIdx.x;
    if (i >= e) return;
    int d = col[i];
    int p = offs[d] + atomicAdd(&cursor[d], 1);
    int s = row[i];
    ssrc[p] = s;
    sw[p]   = dis[s];
}

__global__ __launch_bounds__(256) void agg3_k(const float* __restrict__ x,
                                              float* __restrict__ out,
                                              const int* __restrict__ offs,
                                              const int* __restrict__ ssrc,
                                              const float* __restrict__ sw,
                                              const float* __restrict__ dis, int n) {
    int d = blockIdx.x * 256 + threadIdx.x;
    if (d >= n) return;
    float dd = dis[d];
    float a0 = dd * x[d * 3 + 0];
    float a1 = dd * x[d * 3 + 1];
    float a2 = dd * x[d * 3 + 2];
    int beg = offs[d], end = offs[d + 1];
    for (int e = beg; e < end; ++e) {
        int s = ssrc[e];
        float w = sw[e];
        a0 += w * x[s * 3 + 0];
        a1 += w * x[s * 3 + 1];
        a2 += w * x[s * 3 + 2];
    }
    out[d * 3 + 0] = dd * a0;
    out[d * 3 + 1] = dd * a1;
    out[d * 3 + 2] = dd * a2;
}

// h1 = relu(aggx[N,3] @ W1[3,512] + b1) -> bf16; one WAVE per node, short8 store
__global__ __launch_bounds__(256) void gemm1_k(const float* __restrict__ aggx,
                                               const float* __restrict__ W1,
                                               const float* __restrict__ b1,
                                               __hip_bfloat16* __restrict__ h1, int n) {
    int wave = threadIdx.x >> 6;
    int lane = threadIdx.x & 63;
    int d = blockIdx.x * 4 + wave;
    if (d >= n) return;
    float a0 = aggx[d * 3 + 0], a1 = aggx[d * 3 + 1], a2 = aggx[d * 3 + 2];
    int f0 = lane * 8;
    short8 ov;
#pragma unroll
    for (int j = 0; j < 8; ++j) {
        int f = f0 + j;
        float v = b1[f] + a0 * W1[f] + a1 * W1[512 + f] + a2 * W1[1024 + f];
        __hip_bfloat16 h = __float2bfloat16(fmaxf(v, 0.0f));
        ov[j] = *(short*)&h;
    }
    *(short8*)&h1[(size_t)d * 512 + f0] = ov;
}

__device__ inline float bs2f(short v) {
    return __uint_as_float(((unsigned int)(unsigned short)v) << 16);
}

// aggregation F=512, one WAVE per node, 16B loads, edge loop unrolled x4
__global__ __launch_bounds__(256) void agg512w_k(const __hip_bfloat16* __restrict__ in,
                                                 __hip_bfloat16* __restrict__ out,
                                                 const int* __restrict__ offs,
                                                 const int* __restrict__ ssrc,
                                                 const float* __restrict__ sw,
                                                 const float* __restrict__ dis,
                                                 const float* __restrict__ bias,
                                                 int relu, int n) {
    int wave = threadIdx.x >> 6;
    int lane = threadIdx.x & 63;
    int d = blockIdx.x * 4 + wave;
    if (d >= n) return;
    float dd = dis[d];
    short8 p = *(const short8*)&in[(size_t)d * 512 + lane * 8];
    float acc[8];
#pragma unroll
    for (int j = 0; j < 8; ++j) acc[j] = dd * bs2f(p[j]);

    int beg = offs[d], end = offs[d + 1];
    int e = beg;
    for (; e + 3 < end; e += 4) {
        int s0 = ssrc[e],     s1 = ssrc[e + 1];
        int s2 = ssrc[e + 2], s3 = ssrc[e + 3];
        float w0 = sw[e],     w1 = sw[e + 1];
        float w2 = sw[e + 2], w3 = sw[e + 3];
        short8 q0 = *(const short8*)&in[(size_t)s0 * 512 + lane * 8];
        short8 q1 = *(const short8*)&in[(size_t)s1 * 512 + lane * 8];
        short8 q2 = *(const short8*)&in[(size_t)s2 * 512 + lane * 8];
        short8 q3 = *(const short8*)&in[(size_t)s3 * 512 + lane * 8];
#pragma unroll
        for (int j = 0; j < 8; ++j) acc[j] += w0 * bs2f(q0[j]);
#pragma unroll
        for (int j = 0; j < 8; ++j) acc[j] += w1 * bs2f(q1[j]);
#pragma unroll
        for (int j = 0; j < 8; ++j) acc[j] += w2 * bs2f(q2[j]);
#pragma unroll
        for (int j = 0; j < 8; ++j) acc[j] += w3 * bs2f(q3[j]);
    }
    for (; e < end; ++e) {
        int s0 = ssrc[e];
        float w0 = sw[e];
        short8 q0 = *(const short8*)&in[(size_t)s0 * 512 + lane * 8];
#pragma unroll
        for (int j = 0; j < 8; ++j) acc[j] += w0 * bs2f(q0[j]);
    }

    short8 ov;
#pragma unroll
    for (int j = 0; j < 8; ++j) {
        float v = acc[j] * dd;
        if (bias) v += bias[lane * 8 + j];
        if (relu) v = fmaxf(v, 0.0f);
        __hip_bfloat16 h = __float2bfloat16(v);
        ov[j] = *(short*)&h;
    }
    *(short8*)&out[(size_t)d * 512 + lane * 8] = ov;
}

// tiled transpose + f32->bf16 convert: W[K][N] -> Wt[N][K]
__global__ __launch_bounds__(256) void tcvt_k(const float* __restrict__ W,
                                              __hip_bfloat16* __restrict__ Wt,
                                              int K, int N) {
    __shared__ float tile[32][33];
    int t = threadIdx.x;
    int bn = blockIdx.x * 32;
    int bk = blockIdx.y * 32;
    int c = t & 31, r0 = t >> 5;
#pragma unroll
    for (int j = 0; j < 4; ++j) {
        int r = r0 + j * 8;
        tile[r][c] = W[(size_t)(bk + r) * N + bn + c];
    }
    __syncthreads();
#pragma unroll
    for (int j = 0; j < 4; ++j) {
        int r = r0 + j * 8;
        Wt[(size_t)(bn + r) * K + bk + c] = __float2bfloat16(tile[c][r]);
    }
}

// bf16 MFMA GEMM: C[M,N] = epi(A[M,K] @ Bt[N,K]^T + bias)
// 128x128 tile, BK=32, 4 waves (2x2; wave tile 64x64 = 4x4 16x16x32 MFMA).
// - Fragment-major global_load_lds staging, double-buffered, 1 barrier/iter.
// - Waves 0-1 stage A segments, waves 2-3 stage B segments, via ONE base
//   pointer + 16*K-element stride (register diet for 4 blocks/CU).
// - A rows are read UNGUARDED up to the 128-padded M (Mpad) -> buffers must
//   be allocated with Mpad rows. Stores are guarded by M.
// - XCD swizzle: (1<<lnbx) col-blocks sharing a row-tile share blockIdx%8.
// __launch_bounds__(256,4): target <=128 unified VGPR+AGPR -> 4 blocks/CU
// (LDS 34KB -> 4 blocks fit in 160KB).
__global__ __launch_bounds__(256, 4) void mfma_gemm_k(const __hip_bfloat16* __restrict__ A,
                                                      const __hip_bfloat16* __restrict__ Bt,
                                                      const float* __restrict__ bias,
                                                      __hip_bfloat16* __restrict__ C,
                                                      int M, int N, int K, int relu,
                                                      int lnbx) {
    __shared__ short smem[17408];   // 34816B: 2x8192 staging / 128x136 epi

    int tid  = threadIdx.x;
    int lane = tid & 63;
    int wave = tid >> 6;
    int wm = (wave >> 1) * 64;
    int wn = (wave & 1) * 64;
    int fr = lane & 15;
    int kg = lane >> 4;

    // swizzled block decode
    int b  = blockIdx.x;
    int r8 = b & 7;
    int j  = (b >> 3) & ((1 << lnbx) - 1);
    int g8 = b >> (3 + lnbx);
    int bm = (g8 * 8 + r8) * 128;
    int bn = j * 128;

    // one staging base per thread; wave w covers segments w*4..w*4+3
    const __hip_bfloat16* gbase;
    if (wave < 2) gbase = A  + (size_t)(bm + wave * 64 + fr) * K;
    else          gbase = Bt + (size_t)(bn + (wave - 2) * 64 + fr) * K;
    gbase += kg * 8;
    size_t segstr = (size_t)16 * K;   // 16 rows per segment

    floatx4 acc[4][4] = {};

    // prologue: stage tile 0 into buffer 0
#pragma unroll
    for (int i = 0; i < 4; ++i)
        load16_to_lds(gbase + i * segstr, &smem[(wave * 4 + i) * 512]);
    gbase += 32;

    int cur = 0;
    for (int k0 = 0; k0 < K; k0 += 32) {
        __syncthreads();   // tile[cur] staged; prev ds_reads done
        int nxt = cur ^ 8192;
        if (k0 + 32 < K) {
#pragma unroll
            for (int i = 0; i < 4; ++i)
                load16_to_lds(gbase + i * segstr, &smem[nxt + (wave * 4 + i) * 512]);
            gbase += 32;
        }

        short8 af[4], bf[4];
#pragma unroll
        for (int mi = 0; mi < 4; ++mi)
            af[mi] = *(short8*)&smem[cur + ((wm >> 4) + mi) * 512 + lane * 8];
#pragma unroll
        for (int ni = 0; ni < 4; ++ni)
            bf[ni] = *(short8*)&smem[cur + (8 + (wn >> 4) + ni) * 512 + lane * 8];
#pragma unroll
        for (int mi = 0; mi < 4; ++mi)
#pragma unroll
            for (int ni = 0; ni < 4; ++ni)
                acc[mi][ni] = __builtin_amdgcn_mfma_f32_16x16x32_bf16(
                    af[mi], bf[ni], acc[mi][ni], 0, 0, 0);
        cur = nxt;
    }
    __syncthreads();   // all ds_reads done before smem reuse as Cs

    // epilogue: bias+relu, repack via LDS, coalesced 16B stores
    short* Cs = smem;   // [128][136]
#pragma unroll
    for (int mi = 0; mi < 4; ++mi) {
#pragma unroll
        for (int ni = 0; ni < 4; ++ni) {
            int rl = wm + mi * 16 + (lane >> 4) * 4;
            int cl = wn + ni * 16 + (lane & 15);
            float bv = bias ? bias[bn + cl] : 0.0f;
#pragma unroll
            for (int r = 0; r < 4; ++r) {
                float v = acc[mi][ni][r] + bv;
                if (relu) v = fmaxf(v, 0.0f);
                __hip_bfloat16 h = __float2bfloat16(v);
                Cs[(rl + r) * 136 + cl] = *(short*)&h;
            }
        }
    }
    __syncthreads();
#pragma unroll
    for (int i = 0; i < 8; ++i) {
        int c  = tid + 256 * i;
        int rr = c >> 4;
        int cc = c & 15;
        int grow = bm + rr;
        if (grow < M)
            *(short8*)&C[(size_t)grow * N + bn + cc * 8] =
                *(short8*)&Cs[rr * 136 + cc * 8];
    }
}

// per-graph node counts — LDS histogram
__global__ __launch_bounds__(256) void count_k(const int* __restrict__ batch,
                                               int* __restrict__ gcnt, int n) {
    __shared__ int h[NGRAPH];
    int t = threadIdx.x;
    if (t < NGRAPH) h[t] = 0;
    __syncthreads();
    for (int i = blockIdx.x * 256 + t; i < n; i += gridDim.x * 256)
        atomicAdd(&h[batch[i]], 1);
    __syncthreads();
    if (t < NGRAPH) atomicAdd(&gcnt[t], h[t]);
}

// pooled sums, bf16 input, LDS fp32 accumulators
__global__ __launch_bounds__(256) void pool_k(const __hip_bfloat16* __restrict__ h,
                                              const int* __restrict__ batch,
                                              float* __restrict__ gsum, int n) {
    __shared__ float ls[NGRAPH * 512];
    int t = threadIdx.x;
    for (int i = t; i < NGRAPH * 512; i += 256) ls[i] = 0.0f;
    __syncthreads();
    for (int d = blockIdx.x; d < n; d += gridDim.x) {
        int g = batch[d];
        unsigned int q = *(const unsigned int*)&h[(size_t)d * 512 + 2 * t];
        ls[g * 512 + 2 * t]     += __uint_as_float((q & 0xffffu) << 16);
        ls[g * 512 + 2 * t + 1] += __uint_as_float((q >> 16) << 16);
    }
    __syncthreads();
    for (int i = t; i < NGRAPH * 512; i += 256) atomicAdd(&gsum[i], ls[i]);
}

// head MLP (fp32)
__global__ __launch_bounds__(128) void fc_k(const float* __restrict__ gsum,
                                            const int* __restrict__ gcnt,
                                            const float* __restrict__ fcw1,
                                            const float* __restrict__ fcb1,
                                            const float* __restrict__ fcw2,
                                            const float* __restrict__ fcb2,
                                            float* __restrict__ out) {
    int g = blockIdx.x;
    int t = threadIdx.x;  // 128
    __shared__ float pooled[512];
    __shared__ float red[128];
    float inv = 1.0f / fmaxf((float)gcnt[g], 1.0f);
    for (int i = t; i < 512; i += 128) pooled[i] = gsum[g * 512 + i] * inv;
    __syncthreads();
    float s = fcb1[t];
    for (int k = 0; k < 512; ++k) s += pooled[k] * fcw1[k * 128 + t];
    s = fmaxf(s, 0.0f);
    red[t] = s * fcw2[t];
    __syncthreads();
    for (int off = 64; off > 0; off >>= 1) {
        if (t < off) red[t] += red[t + off];
        __syncthreads();
    }
    if (t == 0) out[g] = red[0] + fcb2[0];
}

extern "C" void kernel_launch(void* const* d_in, const int* in_sizes, int n_in,
                              void* d_out, int out_size, void* d_ws, size_t ws_size,
                              hipStream_t stream) {
    const float* x    = (const float*)d_in[0];
    const int*   ei   = (const int*)d_in[1];   // [2, E]
    const int*   batch= (const int*)d_in[2];
    const float* W1   = (const float*)d_in[3];
    const float* b1   = (const float*)d_in[4];
    const float* W2   = (const float*)d_in[5];
    const float* b2   = (const float*)d_in[6];
    const float* W3   = (const float*)d_in[7];
    const float* b3   = (const float*)d_in[8];
    const float* fcw1 = (const float*)d_in[9];
    const float* fcb1 = (const float*)d_in[10];
    const float* fcw2 = (const float*)d_in[11];
    const float* fcb2 = (const float*)d_in[12];
    float* out = (float*)d_out;

    const int N = in_sizes[0] / 3;      // 50000
    const int E = in_sizes[1] / 2;      // 400000
    const int Mpad = (N + 127) & ~127;  // 50176: GEMM A reads unguarded to Mpad
    const int* row = ei;
    const int* col = ei + E;

    // ---- workspace layout ----
    size_t used = 0;
    auto need = [&](size_t bytes) {
        size_t off = used;
        used += (bytes + 255) & ~(size_t)255;
        return off;
    };
    size_t o_deg  = need((size_t)N * 4);
    size_t o_cur  = need((size_t)N * 4);
    size_t o_dis  = need((size_t)N * 4);
    size_t o_offs = need((size_t)(N + 1) * 4);
    size_t o_ssrc = need((size_t)E * 4);
    size_t o_sw   = need((size_t)E * 4);
    size_t o_aggx = need((size_t)N * 3 * 4);
    size_t o_gsum = need((size_t)NGRAPH * 512 * 4);
    size_t o_gcnt = need((size_t)NGRAPH * 4);
    size_t o_w2t  = need((size_t)512 * 1024 * 2);    // W2^T bf16 [1024][512]
    size_t o_w3t  = need((size_t)1024 * 512 * 2);    // W3^T bf16 [512][1024]
    size_t o_bufX = need((size_t)Mpad * 512 * 2);    // h1 -> g3   (bf16)
    size_t o_bufY = need((size_t)Mpad * 512 * 2);    // agg1 -> h3 (bf16)
    size_t o_bufZ = need((size_t)Mpad * 1024 * 2);   // h2         (bf16)

    if (used > ws_size) {
        hipLaunchKernelGGL(zero_out_k, dim3((out_size + 63) / 64), dim3(64), 0, stream,
                           out, out_size);
        return;
    }

    char* base = (char*)d_ws;
    int*   deg_cnt = (int*)  (base + o_deg);
    int*   cursor  = (int*)  (base + o_cur);
    float* dis     = (float*)(base + o_dis);
    int*   offs    = (int*)  (base + o_offs);
    int*   ssrc    = (int*)  (base + o_ssrc);
    float* sw      = (float*)(base + o_sw);
    float* aggx    = (float*)(base + o_aggx);
    float* gsum    = (float*)(base + o_gsum);
    int*   gcnt    = (int*)  (base + o_gcnt);
    __hip_bfloat16* w2t  = (__hip_bfloat16*)(base + o_w2t);
    __hip_bfloat16* w3t  = (__hip_bfloat16*)(base + o_w3t);
    __hip_bfloat16* bufX = (__hip_bfloat16*)(base + o_bufX);
    __hip_bfloat16* bufY = (__hip_bfloat16*)(base + o_bufY);
    __hip_bfloat16* bufZ = (__hip_bfloat16*)(base + o_bufZ);
    (void)n_in;

    int gN = (N + 255) / 256;
    int gE = (E + 255) / 256;
    int gW = (N + 3) / 4;                         // wave-per-node grids
    int nby8 = (((N + 127) / 128 + 7) / 8) * 8;   // 128-row tiles, padded to x8

    // CSR build + norm
    hipLaunchKernelGGL(init_k, dim3(gN), dim3(256), 0, stream, deg_cnt, cursor, gsum, gcnt, N);
    hipLaunchKernelGGL(deg_k, dim3(gE), dim3(256), 0, stream, col, deg_cnt, E);
    hipLaunchKernelGGL(dis_k, dim3(gN), dim3(256), 0, stream, deg_cnt, dis, N);
    hipLaunchKernelGGL(scan_k, dim3(1), dim3(1024), 0, stream, deg_cnt, offs, N);
    hipLaunchKernelGGL(scatter_k, dim3(gE), dim3(256), 0, stream, row, col, offs, cursor, ssrc, sw, dis, E);

    // weights: transpose + bf16 convert
    hipLaunchKernelGGL(tcvt_k, dim3(1024 / 32, 512 / 32), dim3(256), 0, stream, W2, w2t, 512, 1024);
    hipLaunchKernelGGL(tcvt_k, dim3(512 / 32, 1024 / 32), dim3(256), 0, stream, W3, w3t, 1024, 512);

    // layer 1: agg(F=3) fp32, then 3->512 GEMM -> h1 bf16
    hipLaunchKernelGGL(agg3_k, dim3(gN), dim3(256), 0, stream, x, aggx, offs, ssrc, sw, dis, N);
    hipLaunchKernelGGL(gemm1_k, dim3(gW), dim3(256), 0, stream, aggx, W1, b1, bufX, N);

    // layer 2: agg1 = A_norm h1, h2 = relu(agg1 @ W2 + b2)
    hipLaunchKernelGGL(agg512w_k, dim3(gW), dim3(256), 0, stream, bufX, bufY, offs, ssrc, sw, dis,
                       (const float*)nullptr, 0, N);
    hipLaunchKernelGGL(mfma_gemm_k, dim3(nby8 * 8), dim3(256), 0, stream,
                       bufY, w2t, b2, bufZ, N, 1024, 512, 1, 3);

    // layer 3: g3 = h2 @ W3, h3 = relu(A_norm g3 + b3)
    hipLaunchKernelGGL(mfma_gemm_k, dim3(nby8 * 4), dim3(256), 0, stream,
                       bufZ, w3t, (const float*)nullptr, bufX, N, 512, 1024, 0, 2);
    hipLaunchKernelGGL(agg512w_k, dim3(gW), dim3(256), 0, stream, bufX, bufY, offs, ssrc, sw, dis,
                       b3, 1, N);

    // mean pool + head
    hipLaunchKernelGGL(count_k, dim3(64), dim3(256), 0, stream, batch, gcnt, N);
    hipLaunchKernelGGL(pool_k, dim3(256), dim3(256), 0, stream, bufY, batch, gsum, N);
    hipLaunchKernelGGL(fc_k, dim3(NGRAPH), dim3(128), 0, stream, gsum, gcnt, fcw1, fcb1, fcw2, fcb2, out);
}